// Round 2
// baseline (12116.293 us; speedup 1.0000x reference)
//
#include <hip/hip_runtime.h>
#include <stdint.h>
#include <stddef.h>

// ---------- constants ----------
#define B_    64
#define N_    32
#define NREL_ 992
#define D_    512
#define E_    128
#define H_    512
#define T_    16
#define MROWS (B_ * NREL_)   // 63488
#define MOBJ  (B_ * N_)      // 2048
#define NCHUNK 4
#define CH_   (MROWS / NCHUNK)   // 15872 (divisible by 128)

typedef unsigned short ushort_t;
typedef __attribute__((ext_vector_type(8))) short bf16x8;   // 8 bf16 = 4 VGPRs (MFMA A/B frag)
typedef __attribute__((ext_vector_type(4))) float f32x4;    // MFMA C/D frag

typedef __attribute__((address_space(1))) const void gvoid;
typedef __attribute__((address_space(3))) void lvoid;

__device__ __forceinline__ float bf2f(ushort_t u) {
  union { unsigned int i; float f; } v; v.i = ((unsigned int)u) << 16; return v.f;
}
__device__ __forceinline__ ushort_t f2bf(float f) {   // round-to-nearest-even
  union { float f; unsigned int i; } v; v.f = f;
  unsigned int u = v.i;
  u += 0x7FFFu + ((u >> 16) & 1u);
  return (ushort_t)(u >> 16);
}
__device__ __forceinline__ void gload_lds16(const void* g, void* l) {
  __builtin_amdgcn_global_load_lds((gvoid*)g, (lvoid*)l, 16, 0, 0);
}

// ---------- generic 128x128 MFMA GEMM with 3xBF16 fp32 emulation ----------
// Computes C = act(A @ W + bias) where A, W are logically fp32 held as bf16
// hi/lo pairs. Inner product runs over K'' = 3K:  seg0 = Ahi*Bhi,
// seg1 = Alo*Bhi, seg2 = Ahi*Blo.  Weights pre-expanded: Bt[n][3K] = [hi|hi|lo].
// A storage is split [hi(K) | lo(K)] per row; fetch map seg0->hi, seg1->lo, seg2->hi.
// MODE 0: A rows plain split [M][2K].
// MODE 1: gather rows via offS/offD (element base = node*1024) from entity
//         [node][1024] = [hi512|lo512]; logical row = concat(src512, dst512). K=1024.
// MODE 2: logical row m = concat(ent[m](512), agg[m](128)); ent [m][1024] split,
//         agg (A2) [m][256] split. K=640.
// Output C split: [row][2N] = [hi|lo]. Optional f32 copy to Cf.
template<int MODE, bool RELU, bool WRITE_F32>
__global__ __launch_bounds__(256) void gemm_k(
    const ushort_t* __restrict__ A, const ushort_t* __restrict__ A2,
    const int* __restrict__ offS, const int* __restrict__ offD,
    const ushort_t* __restrict__ Bt, const float* __restrict__ bias,
    ushort_t* __restrict__ C, float* __restrict__ Cf,
    int M, int N, int K)
{
  __shared__ ushort_t As[128 * 64];   // [row][k] rows of 64 bf16 (128B)
  __shared__ ushort_t Bs[128 * 64];   // [col(n)][k]

  const int tid  = threadIdx.x;
  const int lane = tid & 63;
  const int wave = tid >> 6;
  const int m0 = blockIdx.y * 128;
  const int n0 = blockIdx.x * 128;
  const int wr = (wave >> 1) * 64;    // wave row offset in tile
  const int wc = (wave & 1) * 64;     // wave col offset in tile

  const int srow = tid >> 3;          // 0..31: staging row within a 32-row round
  const int scol = (tid & 7) * 8;     // element offset in k (8 bf16 = 16B per lane)

  // per-round global element offsets (k-invariant part)
  long aoff[4]; long aoff2[4];
#pragma unroll
  for (int r = 0; r < 4; ++r) {
    int m = m0 + r * 32 + srow;
    if (MODE == 0)      { aoff[r] = (long)m * (2 * K) + scol; aoff2[r] = 0; }
    else if (MODE == 1) { aoff[r] = (long)offS[m] + scol; aoff2[r] = (long)offD[m] + scol; }
    else                { aoff[r] = (long)m * 1024 + scol; aoff2[r] = (long)m * 256 + scol; }
  }
  long boff[4];
#pragma unroll
  for (int r = 0; r < 4; ++r) boff[r] = (long)(n0 + r * 32 + srow) * (3 * K) + scol;

  f32x4 zero = {0.f, 0.f, 0.f, 0.f};
  f32x4 acc[4][4];
#pragma unroll
  for (int i = 0; i < 4; ++i)
#pragma unroll
    for (int j = 0; j < 4; ++j) acc[i][j] = zero;

  const int Kpp = 3 * K;
  for (int kt = 0; kt < Kpp; kt += 64) {
    const int seg = (kt >= 2 * K) ? 2 : ((kt >= K) ? 1 : 0);
    const int k   = kt - seg * K;
    const bool lop = (seg == 1);      // lo part of A this segment

    // stage A tile (128x64), 4 rounds of 32 rows; LDS dest is wave-uniform base
#pragma unroll
    for (int r = 0; r < 4; ++r) {
      const ushort_t* src;
      if (MODE == 0) {
        src = A + aoff[r] + (lop ? K : 0) + k;
      } else if (MODE == 1) {
        const int inRow = (k < 512) ? k : (k - 512);
        const long base = (k < 512) ? aoff[r] : aoff2[r];
        src = A + base + (lop ? 512 : 0) + inRow;
      } else {
        if (k < 512) src = A  + aoff[r]  + (lop ? 512 : 0) + k;
        else         src = A2 + aoff2[r] + (lop ? 128 : 0) + (k - 512);
      }
      gload_lds16(src, &As[(r * 32 + wave * 8) * 64]);
    }
    // stage B tile (128 cols x 64 k) from expanded weights [N][3K]
#pragma unroll
    for (int r = 0; r < 4; ++r)
      gload_lds16(Bt + boff[r] + kt, &Bs[(r * 32 + wave * 8) * 64]);

    __syncthreads();

#pragma unroll
    for (int kk = 0; kk < 2; ++kk) {
      bf16x8 af[4], bfr[4];
#pragma unroll
      for (int i = 0; i < 4; ++i) {
        af[i]  = *(const bf16x8*)&As[(wr + i * 16 + (lane & 15)) * 64 + kk * 32 + (lane >> 4) * 8];
        bfr[i] = *(const bf16x8*)&Bs[(wc + i * 16 + (lane & 15)) * 64 + kk * 32 + (lane >> 4) * 8];
      }
#pragma unroll
      for (int i = 0; i < 4; ++i)
#pragma unroll
        for (int j = 0; j < 4; ++j)
          acc[i][j] = __builtin_amdgcn_mfma_f32_16x16x32_bf16(af[i], bfr[j], acc[i][j], 0, 0, 0);
    }
    __syncthreads();
  }

  // epilogue: C/D layout col=lane&15, row=(lane>>4)*4+reg; write hi/lo split
  const long strideC = 2 * (long)N;
#pragma unroll
  for (int j = 0; j < 4; ++j) {
    const int col = n0 + wc + j * 16 + (lane & 15);
    const float bv = bias[col];
#pragma unroll
    for (int i = 0; i < 4; ++i) {
      const int rowb = m0 + wr + i * 16 + (lane >> 4) * 4;
#pragma unroll
      for (int r = 0; r < 4; ++r) {
        float v = acc[i][j][r] + bv;
        if (RELU) v = fmaxf(v, 0.f);
        const ushort_t hi = f2bf(v);
        const float lof = v - bf2f(hi);
        C[(long)(rowb + r) * strideC + col]     = hi;
        C[(long)(rowb + r) * strideC + N + col] = f2bf(lof);
        if (WRITE_F32) { if (Cf) Cf[(long)(rowb + r) * N + col] = v; }
      }
    }
  }
}

// ---------- helpers ----------
// split-convert a row-major f32 matrix [R][W] -> [R][2W] bf16 (hi|lo per row)
__global__ void cvt_split_k(const float* __restrict__ x, ushort_t* __restrict__ y,
                            int total, int W) {
  int i = blockIdx.x * 256 + threadIdx.x;
  if (i >= total) return;
  int row = i / W, k = i - row * W;
  float v = x[i];
  ushort_t hi = f2bf(v);
  float lof = v - bf2f(hi);
  y[(long)row * (2 * W) + k]     = hi;
  y[(long)row * (2 * W) + W + k] = f2bf(lof);
}

// W[K][N] f32 -> Bt[n][3K] bf16 = [hi | hi | lo]
__global__ void transpose_cvt_split_k(const float* __restrict__ W, ushort_t* __restrict__ Bt,
                                      int K, int N) {
  int idx = blockIdx.x * 256 + threadIdx.x;
  if (idx >= K * N) return;
  int k = idx / N, n = idx - k * N;
  float v = W[idx];
  ushort_t hi = f2bf(v);
  float lof = v - bf2f(hi);
  ushort_t lo = f2bf(lof);
  long base = (long)n * (3 * K);
  Bt[base + k]         = hi;
  Bt[base + K + k]     = hi;
  Bt[base + 2 * K + k] = lo;
}

__global__ void tables_k(int* __restrict__ offS, int* __restrict__ offD) {
  int m = blockIdx.x * 256 + threadIdx.x;
  if (m >= MROWS) return;
  int b = m / NREL_;
  int e = m - b * NREL_;
  int i = e / 31;
  int jj = e - i * 31;
  int j = jj + (jj >= i ? 1 : 0);
  offS[m] = (b * N_ + i) * 1024;   // element base into entity split rows [node][1024]
  offD[m] = (b * N_ + j) * 1024;
}

// eff [MROWS][256] split -> agg [MOBJ][256] split (sum over 31 incoming edges)
__global__ void scatter_k(const ushort_t* __restrict__ eff, ushort_t* __restrict__ agg) {
  int bn = blockIdx.x;
  int b = bn >> 5, n = bn & 31, f = threadIdx.x;   // 128 threads = E_
  float s = 0.f;
#pragma unroll
  for (int i = 0; i < N_; ++i) {
    if (i == n) continue;
    int jj = (n < i) ? n : (n - 1);
    int e = i * 31 + jj;
    long base = ((long)b * NREL_ + e) * 256;
    s += bf2f(eff[base + f]) + bf2f(eff[base + 128 + f]);
  }
  long obase = ((long)b * N_ + n) * 256;
  ushort_t hi = f2bf(s);
  agg[obase + f]       = hi;
  agg[obase + 128 + f] = f2bf(s - bf2f(hi));
}

__global__ void head_k(const ushort_t* __restrict__ ent, const float* __restrict__ Wl,
                       const float* __restrict__ bl, float* __restrict__ out, int t) {
  int b = blockIdx.x >> 2, n = blockIdx.x & 3, lane = threadIdx.x;   // 64 threads
  const ushort_t* e = ent + (long)(b * N_ + n) * 1024;
  float a0 = 0.f, a1 = 0.f;
  for (int k = lane; k < D_; k += 64) {
    float v = bf2f(e[k]) + bf2f(e[512 + k]);
    a0 += v * Wl[2 * k]; a1 += v * Wl[2 * k + 1];
  }
#pragma unroll
  for (int s = 32; s > 0; s >>= 1) { a0 += __shfl_down(a0, s); a1 += __shfl_down(a1, s); }
  if (lane == 0) {
    out[((long)b * T_ + t) * 8 + n * 2 + 0] = a0 + bl[0];
    out[((long)b * T_ + t) * 8 + n * 2 + 1] = a1 + bl[1];
  }
}

// ---------- launch ----------
extern "C" void kernel_launch(void* const* d_in, const int* in_sizes, int n_in,
                              void* d_out, int out_size, void* d_ws, size_t ws_size,
                              hipStream_t stream) {
  const float* entity = (const float*)d_in[0];
  const float* Wr1 = (const float*)d_in[3];  const float* br1 = (const float*)d_in[4];
  const float* Wr2 = (const float*)d_in[5];  const float* br2 = (const float*)d_in[6];
  const float* Wr3 = (const float*)d_in[7];  const float* br3 = (const float*)d_in[8];
  const float* Wr4 = (const float*)d_in[9];  const float* br4 = (const float*)d_in[10];
  const float* Wo1 = (const float*)d_in[11]; const float* bo1 = (const float*)d_in[12];
  const float* Wo2 = (const float*)d_in[13]; const float* bo2 = (const float*)d_in[14];
  const float* Wl  = (const float*)d_in[15]; const float* bl  = (const float*)d_in[16];

  char* ws = (char*)d_ws;
  size_t off = 0;
  auto alloc = [&](size_t bytes) -> void* {
    void* p = ws + off; off = (off + bytes + 255) & ~(size_t)255; return p;
  };
  // entity state as split rows [node][1024] = [hi512|lo512]
  ushort_t* entP0 = (ushort_t*)alloc((size_t)MOBJ * 1024 * 2);
  ushort_t* entP1 = (ushort_t*)alloc((size_t)MOBJ * 1024 * 2);
  // chunked relational MLP intermediates (CH_ rows)
  ushort_t* H1c = (ushort_t*)alloc((size_t)CH_ * 1024 * 2);   // [CH][2*512]
  ushort_t* H2c = (ushort_t*)alloc((size_t)CH_ * 1024 * 2);   // [CH][2*512]
  ushort_t* H3c = (ushort_t*)alloc((size_t)CH_ * 256 * 2);    // [CH][2*128]
  ushort_t* eff = (ushort_t*)alloc((size_t)MROWS * 256 * 2);  // [MROWS][2*128]
  ushort_t* agg = (ushort_t*)alloc((size_t)MOBJ * 256 * 2);   // [MOBJ][2*128]
  ushort_t* G   = (ushort_t*)alloc((size_t)MOBJ * 1024 * 2);  // [MOBJ][2*512]
  // expanded transposed weights [N][3K]
  ushort_t* Wr1t = (ushort_t*)alloc((size_t)512 * 3072 * 2);
  ushort_t* Wr2t = (ushort_t*)alloc((size_t)512 * 1536 * 2);
  ushort_t* Wr3t = (ushort_t*)alloc((size_t)128 * 1536 * 2);
  ushort_t* Wr4t = (ushort_t*)alloc((size_t)128 * 384 * 2);
  ushort_t* Wo1t = (ushort_t*)alloc((size_t)512 * 1920 * 2);
  ushort_t* Wo2t = (ushort_t*)alloc((size_t)512 * 1536 * 2);
  int* offS = (int*)alloc((size_t)MROWS * 4);
  int* offD = (int*)alloc((size_t)MROWS * 4);
  (void)ws_size; (void)in_sizes; (void)n_in; (void)out_size;

  // per-launch prep
  transpose_cvt_split_k<<<(1024 * 512 + 255) / 256, 256, 0, stream>>>(Wr1, Wr1t, 1024, 512);
  transpose_cvt_split_k<<<(512 * 512 + 255) / 256, 256, 0, stream>>>(Wr2, Wr2t, 512, 512);
  transpose_cvt_split_k<<<(512 * 128 + 255) / 256, 256, 0, stream>>>(Wr3, Wr3t, 512, 128);
  transpose_cvt_split_k<<<(128 * 128 + 255) / 256, 256, 0, stream>>>(Wr4, Wr4t, 128, 128);
  transpose_cvt_split_k<<<(640 * 512 + 255) / 256, 256, 0, stream>>>(Wo1, Wo1t, 640, 512);
  transpose_cvt_split_k<<<(512 * 512 + 255) / 256, 256, 0, stream>>>(Wo2, Wo2t, 512, 512);
  tables_k<<<(MROWS + 255) / 256, 256, 0, stream>>>(offS, offD);
  cvt_split_k<<<(MOBJ * D_ + 255) / 256, 256, 0, stream>>>(entity, entP0, MOBJ * D_, D_);

  float* outP    = (float*)d_out;
  float* lastEnt = outP + (size_t)B_ * T_ * 8;

  ushort_t* cur = entP0;
  ushort_t* nxt = entP1;
  for (int t = 0; t < T_; ++t) {
    for (int c = 0; c < NCHUNK; ++c) {
      const long r0 = (long)c * CH_;
      // GEMM1: gathered [CH,1024] @ Wr1 -> H1c, relu   (K''=3072)
      gemm_k<1, true, false><<<dim3(4, CH_ / 128), 256, 0, stream>>>(
          cur, nullptr, offS + r0, offD + r0, Wr1t, br1, H1c, nullptr, CH_, 512, 1024);
      // GEMM2: H1c @ Wr2 -> H2c, relu
      gemm_k<0, true, false><<<dim3(4, CH_ / 128), 256, 0, stream>>>(
          H1c, nullptr, nullptr, nullptr, Wr2t, br2, H2c, nullptr, CH_, 512, 512);
      // GEMM3: H2c @ Wr3 -> H3c, relu
      gemm_k<0, true, false><<<dim3(1, CH_ / 128), 256, 0, stream>>>(
          H2c, nullptr, nullptr, nullptr, Wr3t, br3, H3c, nullptr, CH_, 128, 512);
      // GEMM4: H3c @ Wr4 -> eff chunk, relu
      gemm_k<0, true, false><<<dim3(1, CH_ / 128), 256, 0, stream>>>(
          H3c, nullptr, nullptr, nullptr, Wr4t, br4, eff + r0 * 256, nullptr, CH_, 128, 128);
    }
    // scatter-add effects to receivers
    scatter_k<<<MOBJ, 128, 0, stream>>>(eff, agg);
    // GEMM5: concat(ent, agg) [2048,640] @ Wo1 -> G, relu
    gemm_k<2, true, false><<<dim3(4, MOBJ / 128), 256, 0, stream>>>(
        cur, agg, nullptr, nullptr, Wo1t, bo1, G, nullptr, MOBJ, 512, 640);
    // GEMM6: G @ Wo2 -> new entity (split bf16 state, + f32 last_entity on final step)
    float* cf = (t == T_ - 1) ? lastEnt : nullptr;
    gemm_k<0, false, true><<<dim3(4, MOBJ / 128), 256, 0, stream>>>(
        G, nullptr, nullptr, nullptr, Wo2t, bo2, nxt, cf, MOBJ, 512, 512);
    // location head on first 4 objects
    head_k<<<256, 64, 0, stream>>>(nxt, Wl, bl, outP, t);

    ushort_t* tmp = cur; cur = nxt; nxt = tmp;
  }
}

// Round 3
// 8399.331 us; speedup vs baseline: 1.4425x; 1.4425x over previous
//
#include <hip/hip_runtime.h>
#include <stdint.h>
#include <stddef.h>

// ---------- constants ----------
#define B_    64
#define N_    32
#define NREL_ 992
#define D_    512
#define E_    128
#define H_    512
#define T_    16
#define MROWS (B_ * NREL_)   // 63488
#define MOBJ  (B_ * N_)      // 2048
#define NCHUNK 4
#define CH_   (MROWS / NCHUNK)   // 15872 (divisible by 128)

typedef unsigned short ushort_t;
typedef __attribute__((ext_vector_type(8))) short bf16x8;   // 8 bf16 = 4 VGPRs (MFMA A/B frag)
typedef __attribute__((ext_vector_type(4))) float f32x4;    // MFMA C/D frag

typedef __attribute__((address_space(1))) const void gvoid;
typedef __attribute__((address_space(3))) void lvoid;

__device__ __forceinline__ float bf2f(ushort_t u) {
  union { unsigned int i; float f; } v; v.i = ((unsigned int)u) << 16; return v.f;
}
__device__ __forceinline__ ushort_t f2bf(float f) {   // round-to-nearest-even
  union { float f; unsigned int i; } v; v.f = f;
  unsigned int u = v.i;
  u += 0x7FFFu + ((u >> 16) & 1u);
  return (ushort_t)(u >> 16);
}
__device__ __forceinline__ void gload_lds16(const void* g, void* l) {
  __builtin_amdgcn_global_load_lds((gvoid*)g, (lvoid*)l, 16, 0, 0);
}

// ---------- generic 128x128 MFMA GEMM with 3xBF16 fp32 emulation ----------
// C = act(A @ W + bias); A, W logically fp32 held as bf16 hi/lo pairs.
// K'' = 3K: seg0 = Ahi*Bhi, seg1 = Alo*Bhi, seg2 = Ahi*Blo.
// Weights pre-expanded: Bt[n][3K] = [hi|hi|lo].
// MODE 0: A rows plain split [M][2K] = [hi K | lo K].
// MODE 2: logical row m = concat(ent[m](512), agg[m](128)); ent [m][1024] split,
//         agg (A2) [m][256] split. K=640.
// Outputs: WBF16 -> C split [row][2N]=[hi|lo]; WF32 -> Cf f32 [row][N] (if non-null).
template<int MODE, bool RELU, bool WBF16, bool WF32>
__global__ __launch_bounds__(256) void gemm_k(
    const ushort_t* __restrict__ A, const ushort_t* __restrict__ A2,
    const ushort_t* __restrict__ Bt, const float* __restrict__ bias,
    ushort_t* __restrict__ C, float* __restrict__ Cf,
    int M, int N, int K)
{
  __shared__ ushort_t As[128 * 64];   // [row][k] rows of 64 bf16 (128B)
  __shared__ ushort_t Bs[128 * 64];   // [col(n)][k]

  const int tid  = threadIdx.x;
  const int lane = tid & 63;
  const int wave = tid >> 6;
  const int m0 = blockIdx.y * 128;
  const int n0 = blockIdx.x * 128;
  const int wr = (wave >> 1) * 64;    // wave row offset in tile
  const int wc = (wave & 1) * 64;     // wave col offset in tile

  const int srow = tid >> 3;          // 0..31: staging row within a 32-row round
  const int scol = (tid & 7) * 8;     // element offset in k (8 bf16 = 16B per lane)

  long aoff[4]; long aoff2[4];
#pragma unroll
  for (int r = 0; r < 4; ++r) {
    int m = m0 + r * 32 + srow;
    if (MODE == 0) { aoff[r] = (long)m * (2 * K) + scol; aoff2[r] = 0; }
    else           { aoff[r] = (long)m * 1024 + scol; aoff2[r] = (long)m * 256 + scol; }
  }
  long boff[4];
#pragma unroll
  for (int r = 0; r < 4; ++r) boff[r] = (long)(n0 + r * 32 + srow) * (3 * K) + scol;

  f32x4 zero = {0.f, 0.f, 0.f, 0.f};
  f32x4 acc[4][4];
#pragma unroll
  for (int i = 0; i < 4; ++i)
#pragma unroll
    for (int j = 0; j < 4; ++j) acc[i][j] = zero;

  const int Kpp = 3 * K;
  for (int kt = 0; kt < Kpp; kt += 64) {
    const int seg = (kt >= 2 * K) ? 2 : ((kt >= K) ? 1 : 0);
    const int k   = kt - seg * K;
    const bool lop = (seg == 1);      // lo part of A this segment

#pragma unroll
    for (int r = 0; r < 4; ++r) {
      const ushort_t* src;
      if (MODE == 0) {
        src = A + aoff[r] + (lop ? K : 0) + k;
      } else {
        if (k < 512) src = A  + aoff[r]  + (lop ? 512 : 0) + k;
        else         src = A2 + aoff2[r] + (lop ? 128 : 0) + (k - 512);
      }
      gload_lds16(src, &As[(r * 32 + wave * 8) * 64]);
    }
#pragma unroll
    for (int r = 0; r < 4; ++r)
      gload_lds16(Bt + boff[r] + kt, &Bs[(r * 32 + wave * 8) * 64]);

    __syncthreads();

#pragma unroll
    for (int kk = 0; kk < 2; ++kk) {
      bf16x8 af[4], bfr[4];
#pragma unroll
      for (int i = 0; i < 4; ++i) {
        af[i]  = *(const bf16x8*)&As[(wr + i * 16 + (lane & 15)) * 64 + kk * 32 + (lane >> 4) * 8];
        bfr[i] = *(const bf16x8*)&Bs[(wc + i * 16 + (lane & 15)) * 64 + kk * 32 + (lane >> 4) * 8];
      }
#pragma unroll
      for (int i = 0; i < 4; ++i)
#pragma unroll
        for (int j = 0; j < 4; ++j)
          acc[i][j] = __builtin_amdgcn_mfma_f32_16x16x32_bf16(af[i], bfr[j], acc[i][j], 0, 0, 0);
    }
    __syncthreads();
  }

  // epilogue: C/D layout col=lane&15, row=(lane>>4)*4+reg
  const long strideC = 2 * (long)N;
#pragma unroll
  for (int j = 0; j < 4; ++j) {
    const int col = n0 + wc + j * 16 + (lane & 15);
    const float bv = bias ? bias[col] : 0.f;
#pragma unroll
    for (int i = 0; i < 4; ++i) {
      const int rowb = m0 + wr + i * 16 + (lane >> 4) * 4;
#pragma unroll
      for (int r = 0; r < 4; ++r) {
        float v = acc[i][j][r] + bv;
        if (RELU) v = fmaxf(v, 0.f);
        if (WBF16) {
          const ushort_t hi = f2bf(v);
          const float lof = v - bf2f(hi);
          C[(long)(rowb + r) * strideC + col]     = hi;
          C[(long)(rowb + r) * strideC + N + col] = f2bf(lof);
        }
        if (WF32) { if (Cf) Cf[(long)(rowb + r) * N + col] = v; }
      }
    }
  }
}

// ---------- helpers ----------
// split-convert a row-major f32 matrix [R][W] -> [R][2W] bf16 (hi|lo per row)
__global__ void cvt_split_k(const float* __restrict__ x, ushort_t* __restrict__ y,
                            int total, int W) {
  int i = blockIdx.x * 256 + threadIdx.x;
  if (i >= total) return;
  int row = i / W, k = i - row * W;
  float v = x[i];
  ushort_t hi = f2bf(v);
  float lof = v - bf2f(hi);
  y[(long)row * (2 * W) + k]     = hi;
  y[(long)row * (2 * W) + W + k] = f2bf(lof);
}

// W[K][N] f32 -> Bt[n][3K] bf16 = [hi | hi | lo]
__global__ void transpose_cvt_split_k(const float* __restrict__ W, ushort_t* __restrict__ Bt,
                                      int K, int N) {
  int idx = blockIdx.x * 256 + threadIdx.x;
  if (idx >= K * N) return;
  int k = idx / N, n = idx - k * N;
  float v = W[idx];
  ushort_t hi = f2bf(v);
  float lof = v - bf2f(hi);
  ushort_t lo = f2bf(lof);
  long base = (long)n * (3 * K);
  Bt[base + k]         = hi;
  Bt[base + K + k]     = hi;
  Bt[base + 2 * K + k] = lo;
}

// Wr1 [1024][512] f32 -> WUVt [1024][1536]: col n<512 from Wr1[k][n] (U = src half),
// n>=512 from Wr1[512+k][n-512] (V = dst half). K=512 inner.
__global__ void tr_uv_k(const float* __restrict__ W, ushort_t* __restrict__ Bt) {
  int idx = blockIdx.x * 256 + threadIdx.x;
  if (idx >= 1024 * 512) return;
  int n = idx >> 9, k = idx & 511;
  float v = (n < 512) ? W[(long)k * 512 + n] : W[(long)(512 + k) * 512 + (n - 512)];
  ushort_t hi = f2bf(v);
  float lof = v - bf2f(hi);
  long base = (long)n * 1536;
  Bt[base + k]        = hi;
  Bt[base + 512 + k]  = hi;
  Bt[base + 1024 + k] = f2bf(lof);
}

__global__ void tables_k(int* __restrict__ srcN, int* __restrict__ dstN) {
  int m = blockIdx.x * 256 + threadIdx.x;
  if (m >= MROWS) return;
  int b = m / NREL_;
  int e = m - b * NREL_;
  int i = e / 31;
  int jj = e - i * 31;
  int j = jj + (jj >= i ? 1 : 0);
  srcN[m] = b * N_ + i;
  dstN[m] = b * N_ + j;
}

// H1c[rlocal] = relu(UV[src].U + UV[dst].V + br1), split hi/lo. 2 rows per block.
__global__ __launch_bounds__(256) void assemble_h1_k(
    const float* __restrict__ UV, const int* __restrict__ srcN,
    const int* __restrict__ dstN, const float* __restrict__ br1,
    ushort_t* __restrict__ H1c, long r0) {
  const int rlocal = blockIdx.x * 2 + (threadIdx.x >> 7);
  const long m = r0 + rlocal;
  const int k0 = (threadIdx.x & 127) * 4;
  const float4 u  = *(const float4*)&UV[(long)srcN[m] * 1024 + k0];
  const float4 w  = *(const float4*)&UV[(long)dstN[m] * 1024 + 512 + k0];
  const float4 bv = *(const float4*)&br1[k0];
  float v0 = fmaxf(u.x + w.x + bv.x, 0.f);
  float v1 = fmaxf(u.y + w.y + bv.y, 0.f);
  float v2 = fmaxf(u.z + w.z + bv.z, 0.f);
  float v3 = fmaxf(u.w + w.w + bv.w, 0.f);
  ushort4 hi, lo;
  hi.x = f2bf(v0); lo.x = f2bf(v0 - bf2f(hi.x));
  hi.y = f2bf(v1); lo.y = f2bf(v1 - bf2f(hi.y));
  hi.z = f2bf(v2); lo.z = f2bf(v2 - bf2f(hi.z));
  hi.w = f2bf(v3); lo.w = f2bf(v3 - bf2f(hi.w));
  *(ushort4*)&H1c[(long)rlocal * 1024 + k0]       = hi;
  *(ushort4*)&H1c[(long)rlocal * 1024 + 512 + k0] = lo;
}

// eff [MROWS][256] split -> agg [MOBJ][256] split (sum over 31 incoming edges)
__global__ void scatter_k(const ushort_t* __restrict__ eff, ushort_t* __restrict__ agg) {
  int bn = blockIdx.x;
  int b = bn >> 5, n = bn & 31, f = threadIdx.x;   // 128 threads = E_
  float s = 0.f;
#pragma unroll
  for (int i = 0; i < N_; ++i) {
    if (i == n) continue;
    int jj = (n < i) ? n : (n - 1);
    int e = i * 31 + jj;
    long base = ((long)b * NREL_ + e) * 256;
    s += bf2f(eff[base + f]) + bf2f(eff[base + 128 + f]);
  }
  long obase = ((long)b * N_ + n) * 256;
  ushort_t hi = f2bf(s);
  agg[obase + f]       = hi;
  agg[obase + 128 + f] = f2bf(s - bf2f(hi));
}

__global__ void head_k(const ushort_t* __restrict__ ent, const float* __restrict__ Wl,
                       const float* __restrict__ bl, float* __restrict__ out, int t) {
  int b = blockIdx.x >> 2, n = blockIdx.x & 3, lane = threadIdx.x;   // 64 threads
  const ushort_t* e = ent + (long)(b * N_ + n) * 1024;
  float a0 = 0.f, a1 = 0.f;
  for (int k = lane; k < D_; k += 64) {
    float v = bf2f(e[k]) + bf2f(e[512 + k]);
    a0 += v * Wl[2 * k]; a1 += v * Wl[2 * k + 1];
  }
#pragma unroll
  for (int s = 32; s > 0; s >>= 1) { a0 += __shfl_down(a0, s); a1 += __shfl_down(a1, s); }
  if (lane == 0) {
    out[((long)b * T_ + t) * 8 + n * 2 + 0] = a0 + bl[0];
    out[((long)b * T_ + t) * 8 + n * 2 + 1] = a1 + bl[1];
  }
}

// ---------- launch ----------
extern "C" void kernel_launch(void* const* d_in, const int* in_sizes, int n_in,
                              void* d_out, int out_size, void* d_ws, size_t ws_size,
                              hipStream_t stream) {
  const float* entity = (const float*)d_in[0];
  const float* Wr1 = (const float*)d_in[3];  const float* br1 = (const float*)d_in[4];
  const float* Wr2 = (const float*)d_in[5];  const float* br2 = (const float*)d_in[6];
  const float* Wr3 = (const float*)d_in[7];  const float* br3 = (const float*)d_in[8];
  const float* Wr4 = (const float*)d_in[9];  const float* br4 = (const float*)d_in[10];
  const float* Wo1 = (const float*)d_in[11]; const float* bo1 = (const float*)d_in[12];
  const float* Wo2 = (const float*)d_in[13]; const float* bo2 = (const float*)d_in[14];
  const float* Wl  = (const float*)d_in[15]; const float* bl  = (const float*)d_in[16];

  char* ws = (char*)d_ws;
  size_t off = 0;
  auto alloc = [&](size_t bytes) -> void* {
    void* p = ws + off; off = (off + bytes + 255) & ~(size_t)255; return p;
  };
  // entity state as split rows [node][1024] = [hi512|lo512]
  ushort_t* entP0 = (ushort_t*)alloc((size_t)MOBJ * 1024 * 2);
  ushort_t* entP1 = (ushort_t*)alloc((size_t)MOBJ * 1024 * 2);
  // object-level layer-1 products: UV[node][1024] f32 = [U(512) | V(512)]
  float* UV = (float*)alloc((size_t)MOBJ * 1024 * 4);
  // chunked relational MLP intermediates
  ushort_t* H1c = (ushort_t*)alloc((size_t)CH_ * 1024 * 2);   // [CH][2*512]
  ushort_t* H2c = (ushort_t*)alloc((size_t)CH_ * 1024 * 2);   // [CH][2*512]
  ushort_t* H3  = (ushort_t*)alloc((size_t)MROWS * 256 * 2);  // [MROWS][2*128] (full)
  ushort_t* eff = (ushort_t*)alloc((size_t)MROWS * 256 * 2);  // [MROWS][2*128]
  ushort_t* agg = (ushort_t*)alloc((size_t)MOBJ * 256 * 2);   // [MOBJ][2*128]
  ushort_t* G   = (ushort_t*)alloc((size_t)MOBJ * 1024 * 2);  // [MOBJ][2*512]
  // expanded transposed weights [N][3K]
  ushort_t* WUVt = (ushort_t*)alloc((size_t)1024 * 1536 * 2);
  ushort_t* Wr2t = (ushort_t*)alloc((size_t)512 * 1536 * 2);
  ushort_t* Wr3t = (ushort_t*)alloc((size_t)128 * 1536 * 2);
  ushort_t* Wr4t = (ushort_t*)alloc((size_t)128 * 384 * 2);
  ushort_t* Wo1t = (ushort_t*)alloc((size_t)512 * 1920 * 2);
  ushort_t* Wo2t = (ushort_t*)alloc((size_t)512 * 1536 * 2);
  int* srcN = (int*)alloc((size_t)MROWS * 4);
  int* dstN = (int*)alloc((size_t)MROWS * 4);
  (void)ws_size; (void)in_sizes; (void)n_in; (void)out_size;

  // per-launch prep
  tr_uv_k<<<(1024 * 512 + 255) / 256, 256, 0, stream>>>(Wr1, WUVt);
  transpose_cvt_split_k<<<(512 * 512 + 255) / 256, 256, 0, stream>>>(Wr2, Wr2t, 512, 512);
  transpose_cvt_split_k<<<(512 * 128 + 255) / 256, 256, 0, stream>>>(Wr3, Wr3t, 512, 128);
  transpose_cvt_split_k<<<(128 * 128 + 255) / 256, 256, 0, stream>>>(Wr4, Wr4t, 128, 128);
  transpose_cvt_split_k<<<(640 * 512 + 255) / 256, 256, 0, stream>>>(Wo1, Wo1t, 640, 512);
  transpose_cvt_split_k<<<(512 * 512 + 255) / 256, 256, 0, stream>>>(Wo2, Wo2t, 512, 512);
  tables_k<<<(MROWS + 255) / 256, 256, 0, stream>>>(srcN, dstN);
  cvt_split_k<<<(MOBJ * D_ + 255) / 256, 256, 0, stream>>>(entity, entP0, MOBJ * D_, D_);

  float* outP    = (float*)d_out;
  float* lastEnt = outP + (size_t)B_ * T_ * 8;

  ushort_t* cur = entP0;
  ushort_t* nxt = entP1;
  for (int t = 0; t < T_; ++t) {
    // UV = ent @ [Wr1_top | Wr1_bot]  (f32 out, no bias/relu)  [2048 x 1024], K=512
    gemm_k<0, false, false, true><<<dim3(8, MOBJ / 128), 256, 0, stream>>>(
        cur, nullptr, WUVt, nullptr, nullptr, UV, MOBJ, 1024, 512);

    for (int c = 0; c < NCHUNK; ++c) {
      const long r0 = (long)c * CH_;
      // H1c = relu(UV[src].U + UV[dst].V + br1), split
      assemble_h1_k<<<CH_ / 2, 256, 0, stream>>>(UV, srcN, dstN, br1, H1c, r0);
      // GEMM2: H1c @ Wr2 -> H2c, relu
      gemm_k<0, true, true, false><<<dim3(4, CH_ / 128), 256, 0, stream>>>(
          H1c, nullptr, Wr2t, br2, H2c, nullptr, CH_, 512, 512);
      // GEMM3: H2c @ Wr3 -> H3 chunk, relu
      gemm_k<0, true, true, false><<<dim3(1, CH_ / 128), 256, 0, stream>>>(
          H2c, nullptr, Wr3t, br3, H3 + r0 * 256, nullptr, CH_, 128, 512);
    }
    // GEMM4: H3 @ Wr4 -> eff (full M), relu
    gemm_k<0, true, true, false><<<dim3(1, MROWS / 128), 256, 0, stream>>>(
        H3, nullptr, Wr4t, br4, eff, nullptr, MROWS, 128, 128);
    // scatter-add effects to receivers
    scatter_k<<<MOBJ, 128, 0, stream>>>(eff, agg);
    // GEMM5: concat(ent, agg) [2048,640] @ Wo1 -> G, relu
    gemm_k<2, true, true, false><<<dim3(4, MOBJ / 128), 256, 0, stream>>>(
        cur, agg, Wo1t, bo1, G, nullptr, MOBJ, 512, 640);
    // GEMM6: G @ Wo2 -> new entity (split bf16 state, + f32 last_entity on final step)
    float* cf = (t == T_ - 1) ? lastEnt : nullptr;
    gemm_k<0, false, true, true><<<dim3(4, MOBJ / 128), 256, 0, stream>>>(
        G, nullptr, Wo2t, bo2, nxt, cf, MOBJ, 512, 512);
    // location head on first 4 objects
    head_k<<<256, 64, 0, stream>>>(nxt, Wl, bl, outP, t);

    ushort_t* tmp = cur; cur = nxt; nxt = tmp;
  }
}

// Round 4
// 7211.563 us; speedup vs baseline: 1.6801x; 1.1647x over previous
//
#include <hip/hip_runtime.h>
#include <stdint.h>
#include <stddef.h>

// ---------- constants ----------
#define B_    64
#define N_    32
#define NREL_ 992
#define D_    512
#define E_    128
#define H_    512
#define T_    16
#define MROWS (B_ * NREL_)   // 63488
#define MOBJ  (B_ * N_)      // 2048

typedef unsigned short ushort_t;
typedef __attribute__((ext_vector_type(8))) short bf16x8;   // 8 bf16 = 4 VGPRs (MFMA A/B frag)
typedef __attribute__((ext_vector_type(4))) float f32x4;    // MFMA C/D frag

typedef __attribute__((address_space(1))) const void gvoid;
typedef __attribute__((address_space(3))) void lvoid;

__device__ __forceinline__ float bf2f(ushort_t u) {
  union { unsigned int i; float f; } v; v.i = ((unsigned int)u) << 16; return v.f;
}
__device__ __forceinline__ ushort_t f2bf(float f) {   // round-to-nearest-even
  union { float f; unsigned int i; } v; v.f = f;
  unsigned int u = v.i;
  u += 0x7FFFu + ((u >> 16) & 1u);
  return (ushort_t)(u >> 16);
}
__device__ __forceinline__ void gload_lds16(const void* g, void* l) {
  __builtin_amdgcn_global_load_lds((gvoid*)g, (lvoid*)l, 16, 0, 0);
}

// ---------- generic 128x128 MFMA GEMM with 3xBF16 fp32 emulation ----------
// C = act(A @ W + bias); A, W logically fp32 held as bf16 hi/lo pairs.
// K'' = 3K: seg0 = Ahi*Bhi, seg1 = Alo*Bhi, seg2 = Ahi*Blo.
// Weights pre-expanded: Bt[n][3K] = [hi|hi|lo].
// MODE 0: A rows plain split [M][2K] = [hi K | lo K].
// MODE 2: logical row m = concat(ent[m](512), agg[m](128)); ent [m][1024] split,
//         agg (A2) [m][256] split. K=640.
// Outputs: WBF16 -> C split [row][2N]=[hi|lo]; WF32 -> Cf f32 [row][N] (if non-null).
template<int MODE, bool RELU, bool WBF16, bool WF32>
__global__ __launch_bounds__(256) void gemm_k(
    const ushort_t* __restrict__ A, const ushort_t* __restrict__ A2,
    const ushort_t* __restrict__ Bt, const float* __restrict__ bias,
    ushort_t* __restrict__ C, float* __restrict__ Cf,
    int M, int N, int K)
{
  __shared__ ushort_t As[128 * 64];   // [row][k] rows of 64 bf16 (128B)
  __shared__ ushort_t Bs[128 * 64];   // [col(n)][k]

  const int tid  = threadIdx.x;
  const int lane = tid & 63;
  const int wave = tid >> 6;

  // bijective XCD-chunked tile remap (m204): each XCD gets a contiguous tile
  // range so the 4 grid-x blocks sharing an A row-panel land on one XCD's L2.
  const int nwg  = gridDim.x * gridDim.y;
  const int orig = blockIdx.y * gridDim.x + blockIdx.x;
  const int xcd  = orig & 7;
  const int q    = nwg >> 3, r = nwg & 7;
  const int nid  = (xcd < r ? xcd * (q + 1) : r * (q + 1) + (xcd - r) * q) + (orig >> 3);
  const int m0 = (nid / gridDim.x) * 128;
  const int n0 = (nid % gridDim.x) * 128;

  const int wr = (wave >> 1) * 64;    // wave row offset in tile
  const int wc = (wave & 1) * 64;     // wave col offset in tile

  const int srow = tid >> 3;          // 0..31: staging row within a 32-row round
  const int scol = (tid & 7) * 8;     // element offset in k (8 bf16 = 16B per lane)

  long aoff[4]; long aoff2[4];
#pragma unroll
  for (int rr = 0; rr < 4; ++rr) {
    int m = m0 + rr * 32 + srow;
    if (MODE == 0) { aoff[rr] = (long)m * (2 * K) + scol; aoff2[rr] = 0; }
    else           { aoff[rr] = (long)m * 1024 + scol; aoff2[rr] = (long)m * 256 + scol; }
  }
  long boff[4];
#pragma unroll
  for (int rr = 0; rr < 4; ++rr) boff[rr] = (long)(n0 + rr * 32 + srow) * (3 * K) + scol;

  f32x4 zero = {0.f, 0.f, 0.f, 0.f};
  f32x4 acc[4][4];
#pragma unroll
  for (int i = 0; i < 4; ++i)
#pragma unroll
    for (int j = 0; j < 4; ++j) acc[i][j] = zero;

  const int Kpp = 3 * K;
  for (int kt = 0; kt < Kpp; kt += 64) {
    const int seg = (kt >= 2 * K) ? 2 : ((kt >= K) ? 1 : 0);
    const int k   = kt - seg * K;
    const bool lop = (seg == 1);      // lo part of A this segment

#pragma unroll
    for (int rr = 0; rr < 4; ++rr) {
      const ushort_t* src;
      if (MODE == 0) {
        src = A + aoff[rr] + (lop ? K : 0) + k;
      } else {
        if (k < 512) src = A  + aoff[rr]  + (lop ? 512 : 0) + k;
        else         src = A2 + aoff2[rr] + (lop ? 128 : 0) + (k - 512);
      }
      gload_lds16(src, &As[(rr * 32 + wave * 8) * 64]);
    }
#pragma unroll
    for (int rr = 0; rr < 4; ++rr)
      gload_lds16(Bt + boff[rr] + kt, &Bs[(rr * 32 + wave * 8) * 64]);

    __syncthreads();

#pragma unroll
    for (int kk = 0; kk < 2; ++kk) {
      bf16x8 af[4], bfr[4];
#pragma unroll
      for (int i = 0; i < 4; ++i) {
        af[i]  = *(const bf16x8*)&As[(wr + i * 16 + (lane & 15)) * 64 + kk * 32 + (lane >> 4) * 8];
        bfr[i] = *(const bf16x8*)&Bs[(wc + i * 16 + (lane & 15)) * 64 + kk * 32 + (lane >> 4) * 8];
      }
#pragma unroll
      for (int i = 0; i < 4; ++i)
#pragma unroll
        for (int j = 0; j < 4; ++j)
          acc[i][j] = __builtin_amdgcn_mfma_f32_16x16x32_bf16(af[i], bfr[j], acc[i][j], 0, 0, 0);
    }
    __syncthreads();
  }

  // epilogue: C/D layout col=lane&15, row=(lane>>4)*4+reg
  const long strideC = 2 * (long)N;
#pragma unroll
  for (int j = 0; j < 4; ++j) {
    const int col = n0 + wc + j * 16 + (lane & 15);
    const float bv = bias ? bias[col] : 0.f;
#pragma unroll
    for (int i = 0; i < 4; ++i) {
      const int rowb = m0 + wr + i * 16 + (lane >> 4) * 4;
#pragma unroll
      for (int rr = 0; rr < 4; ++rr) {
        float v = acc[i][j][rr] + bv;
        if (RELU) v = fmaxf(v, 0.f);
        if (WBF16) {
          const ushort_t hi = f2bf(v);
          const float lof = v - bf2f(hi);
          C[(long)(rowb + rr) * strideC + col]     = hi;
          C[(long)(rowb + rr) * strideC + N + col] = f2bf(lof);
        }
        if (WF32) { if (Cf) Cf[(long)(rowb + rr) * N + col] = v; }
      }
    }
  }
}

// ---------- helpers ----------
// split-convert a row-major f32 matrix [R][W] -> [R][2W] bf16 (hi|lo per row)
__global__ void cvt_split_k(const float* __restrict__ x, ushort_t* __restrict__ y,
                            int total, int W) {
  int i = blockIdx.x * 256 + threadIdx.x;
  if (i >= total) return;
  int row = i / W, k = i - row * W;
  float v = x[i];
  ushort_t hi = f2bf(v);
  float lof = v - bf2f(hi);
  y[(long)row * (2 * W) + k]     = hi;
  y[(long)row * (2 * W) + W + k] = f2bf(lof);
}

// W[K][N] f32 -> Bt[n][3K] bf16 = [hi | hi | lo]
__global__ void transpose_cvt_split_k(const float* __restrict__ W, ushort_t* __restrict__ Bt,
                                      int K, int N) {
  int idx = blockIdx.x * 256 + threadIdx.x;
  if (idx >= K * N) return;
  int k = idx / N, n = idx - k * N;
  float v = W[idx];
  ushort_t hi = f2bf(v);
  float lof = v - bf2f(hi);
  ushort_t lo = f2bf(lof);
  long base = (long)n * (3 * K);
  Bt[base + k]         = hi;
  Bt[base + K + k]     = hi;
  Bt[base + 2 * K + k] = lo;
}

// Wr1 [1024][512] f32 -> WUVt [1024][1536]: col n<512 from Wr1[k][n] (U = src half),
// n>=512 from Wr1[512+k][n-512] (V = dst half). K=512 inner.
__global__ void tr_uv_k(const float* __restrict__ W, ushort_t* __restrict__ Bt) {
  int idx = blockIdx.x * 256 + threadIdx.x;
  if (idx >= 1024 * 512) return;
  int n = idx >> 9, k = idx & 511;
  float v = (n < 512) ? W[(long)k * 512 + n] : W[(long)(512 + k) * 512 + (n - 512)];
  ushort_t hi = f2bf(v);
  float lof = v - bf2f(hi);
  long base = (long)n * 1536;
  Bt[base + k]        = hi;
  Bt[base + 512 + k]  = hi;
  Bt[base + 1024 + k] = f2bf(lof);
}

__global__ void tables_k(int* __restrict__ srcN, int* __restrict__ dstN) {
  int m = blockIdx.x * 256 + threadIdx.x;
  if (m >= MROWS) return;
  int b = m / NREL_;
  int e = m - b * NREL_;
  int i = e / 31;
  int jj = e - i * 31;
  int j = jj + (jj >= i ? 1 : 0);
  srcN[m] = b * N_ + i;
  dstN[m] = b * N_ + j;
}

// H1c[rlocal] = relu(UV[src].U + UV[dst].V + br1), split hi/lo. 2 rows per block.
__global__ __launch_bounds__(256) void assemble_h1_k(
    const float* __restrict__ UV, const int* __restrict__ srcN,
    const int* __restrict__ dstN, const float* __restrict__ br1,
    ushort_t* __restrict__ H1c, long r0) {
  const int rlocal = blockIdx.x * 2 + (threadIdx.x >> 7);
  const long m = r0 + rlocal;
  const int k0 = (threadIdx.x & 127) * 4;
  const float4 u  = *(const float4*)&UV[(long)srcN[m] * 1024 + k0];
  const float4 w  = *(const float4*)&UV[(long)dstN[m] * 1024 + 512 + k0];
  const float4 bv = *(const float4*)&br1[k0];
  float v0 = fmaxf(u.x + w.x + bv.x, 0.f);
  float v1 = fmaxf(u.y + w.y + bv.y, 0.f);
  float v2 = fmaxf(u.z + w.z + bv.z, 0.f);
  float v3 = fmaxf(u.w + w.w + bv.w, 0.f);
  ushort4 hi, lo;
  hi.x = f2bf(v0); lo.x = f2bf(v0 - bf2f(hi.x));
  hi.y = f2bf(v1); lo.y = f2bf(v1 - bf2f(hi.y));
  hi.z = f2bf(v2); lo.z = f2bf(v2 - bf2f(hi.z));
  hi.w = f2bf(v3); lo.w = f2bf(v3 - bf2f(hi.w));
  *(ushort4*)&H1c[(long)rlocal * 1024 + k0]       = hi;
  *(ushort4*)&H1c[(long)rlocal * 1024 + 512 + k0] = lo;
}

// eff [MROWS][256] split -> agg [MOBJ][256] split (sum over 31 incoming edges)
__global__ void scatter_k(const ushort_t* __restrict__ eff, ushort_t* __restrict__ agg) {
  int bn = blockIdx.x;
  int b = bn >> 5, n = bn & 31, f = threadIdx.x;   // 128 threads = E_
  float s = 0.f;
#pragma unroll
  for (int i = 0; i < N_; ++i) {
    if (i == n) continue;
    int jj = (n < i) ? n : (n - 1);
    int e = i * 31 + jj;
    long base = ((long)b * NREL_ + e) * 256;
    s += bf2f(eff[base + f]) + bf2f(eff[base + 128 + f]);
  }
  long obase = ((long)b * N_ + n) * 256;
  ushort_t hi = f2bf(s);
  agg[obase + f]       = hi;
  agg[obase + 128 + f] = f2bf(s - bf2f(hi));
}

__global__ void head_k(const ushort_t* __restrict__ ent, const float* __restrict__ Wl,
                       const float* __restrict__ bl, float* __restrict__ out, int t) {
  int b = blockIdx.x >> 2, n = blockIdx.x & 3, lane = threadIdx.x;   // 64 threads
  const ushort_t* e = ent + (long)(b * N_ + n) * 1024;
  float a0 = 0.f, a1 = 0.f;
  for (int k = lane; k < D_; k += 64) {
    float v = bf2f(e[k]) + bf2f(e[512 + k]);
    a0 += v * Wl[2 * k]; a1 += v * Wl[2 * k + 1];
  }
#pragma unroll
  for (int s = 32; s > 0; s >>= 1) { a0 += __shfl_down(a0, s); a1 += __shfl_down(a1, s); }
  if (lane == 0) {
    out[((long)b * T_ + t) * 8 + n * 2 + 0] = a0 + bl[0];
    out[((long)b * T_ + t) * 8 + n * 2 + 1] = a1 + bl[1];
  }
}

// ---------- launch ----------
extern "C" void kernel_launch(void* const* d_in, const int* in_sizes, int n_in,
                              void* d_out, int out_size, void* d_ws, size_t ws_size,
                              hipStream_t stream) {
  const float* entity = (const float*)d_in[0];
  const float* Wr1 = (const float*)d_in[3];  const float* br1 = (const float*)d_in[4];
  const float* Wr2 = (const float*)d_in[5];  const float* br2 = (const float*)d_in[6];
  const float* Wr3 = (const float*)d_in[7];  const float* br3 = (const float*)d_in[8];
  const float* Wr4 = (const float*)d_in[9];  const float* br4 = (const float*)d_in[10];
  const float* Wo1 = (const float*)d_in[11]; const float* bo1 = (const float*)d_in[12];
  const float* Wo2 = (const float*)d_in[13]; const float* bo2 = (const float*)d_in[14];
  const float* Wl  = (const float*)d_in[15]; const float* bl  = (const float*)d_in[16];

  // fixed-size buffers ≈ 62.5 MB; chunk buffers = 2 * (MROWS/nchunk) * 1024 * 2 B
  const size_t fixedBytes = (size_t)70 * 1024 * 1024;   // fixed allocs + padding slack
  int nchunk = 4;
  for (int c = 1; c <= 4; c *= 2) {
    size_t tot = fixedBytes + 2 * ((size_t)(MROWS / c) * 1024 * 2);
    if (tot <= ws_size) { nchunk = c; break; }
  }
  const int CH = MROWS / nchunk;

  char* ws = (char*)d_ws;
  size_t off = 0;
  auto alloc = [&](size_t bytes) -> void* {
    void* p = ws + off; off = (off + bytes + 255) & ~(size_t)255; return p;
  };
  // entity state as split rows [node][1024] = [hi512|lo512]
  ushort_t* entP0 = (ushort_t*)alloc((size_t)MOBJ * 1024 * 2);
  ushort_t* entP1 = (ushort_t*)alloc((size_t)MOBJ * 1024 * 2);
  // object-level layer-1 products: UV[node][1024] f32 = [U(512) | V(512)]
  float* UV = (float*)alloc((size_t)MOBJ * 1024 * 4);
  // H3 [MROWS][2*128]; GEMM4 overwrites it in place with eff
  ushort_t* H3  = (ushort_t*)alloc((size_t)MROWS * 256 * 2);
  ushort_t* agg = (ushort_t*)alloc((size_t)MOBJ * 256 * 2);
  ushort_t* G   = (ushort_t*)alloc((size_t)MOBJ * 1024 * 2);
  // expanded transposed weights [N][3K]
  ushort_t* WUVt = (ushort_t*)alloc((size_t)1024 * 1536 * 2);
  ushort_t* Wr2t = (ushort_t*)alloc((size_t)512 * 1536 * 2);
  ushort_t* Wr3t = (ushort_t*)alloc((size_t)128 * 1536 * 2);
  ushort_t* Wr4t = (ushort_t*)alloc((size_t)128 * 384 * 2);
  ushort_t* Wo1t = (ushort_t*)alloc((size_t)512 * 1920 * 2);
  ushort_t* Wo2t = (ushort_t*)alloc((size_t)512 * 1536 * 2);
  int* srcN = (int*)alloc((size_t)MROWS * 4);
  int* dstN = (int*)alloc((size_t)MROWS * 4);
  // chunk-sized intermediates (largest allocs last)
  ushort_t* H1c = (ushort_t*)alloc((size_t)CH * 1024 * 2);
  ushort_t* H2c = (ushort_t*)alloc((size_t)CH * 1024 * 2);
  (void)in_sizes; (void)n_in; (void)out_size;

  // per-launch prep
  tr_uv_k<<<(1024 * 512 + 255) / 256, 256, 0, stream>>>(Wr1, WUVt);
  transpose_cvt_split_k<<<(512 * 512 + 255) / 256, 256, 0, stream>>>(Wr2, Wr2t, 512, 512);
  transpose_cvt_split_k<<<(512 * 128 + 255) / 256, 256, 0, stream>>>(Wr3, Wr3t, 512, 128);
  transpose_cvt_split_k<<<(128 * 128 + 255) / 256, 256, 0, stream>>>(Wr4, Wr4t, 128, 128);
  transpose_cvt_split_k<<<(640 * 512 + 255) / 256, 256, 0, stream>>>(Wo1, Wo1t, 640, 512);
  transpose_cvt_split_k<<<(512 * 512 + 255) / 256, 256, 0, stream>>>(Wo2, Wo2t, 512, 512);
  tables_k<<<(MROWS + 255) / 256, 256, 0, stream>>>(srcN, dstN);
  cvt_split_k<<<(MOBJ * D_ + 255) / 256, 256, 0, stream>>>(entity, entP0, MOBJ * D_, D_);

  float* outP    = (float*)d_out;
  float* lastEnt = outP + (size_t)B_ * T_ * 8;

  ushort_t* cur = entP0;
  ushort_t* nxt = entP1;
  for (int t = 0; t < T_; ++t) {
    // UV = ent @ [Wr1_top | Wr1_bot]  (f32 out, no bias/relu)  [2048 x 1024], K=512
    gemm_k<0, false, false, true><<<dim3(8, MOBJ / 128), 256, 0, stream>>>(
        cur, nullptr, WUVt, nullptr, nullptr, UV, MOBJ, 1024, 512);

    for (int c = 0; c < nchunk; ++c) {
      const long r0 = (long)c * CH;
      // H1c = relu(UV[src].U + UV[dst].V + br1), split
      assemble_h1_k<<<CH / 2, 256, 0, stream>>>(UV, srcN, dstN, br1, H1c, r0);
      // GEMM2: H1c @ Wr2 -> H2c, relu
      gemm_k<0, true, true, false><<<dim3(4, CH / 128), 256, 0, stream>>>(
          H1c, nullptr, Wr2t, br2, H2c, nullptr, CH, 512, 512);
      // GEMM3: H2c @ Wr3 -> H3 chunk, relu
      gemm_k<0, true, true, false><<<dim3(1, CH / 128), 256, 0, stream>>>(
          H2c, nullptr, Wr3t, br3, H3 + r0 * 256, nullptr, CH, 128, 512);
    }
    // GEMM4: H3 @ Wr4 -> eff IN PLACE over H3 (block y touches only its own rows)
    gemm_k<0, true, true, false><<<dim3(1, MROWS / 128), 256, 0, stream>>>(
        H3, nullptr, Wr4t, br4, H3, nullptr, MROWS, 128, 128);
    // scatter-add effects to receivers
    scatter_k<<<MOBJ, 128, 0, stream>>>(H3, agg);
    // GEMM5: concat(ent, agg) [2048,640] @ Wo1 -> G, relu
    gemm_k<2, true, true, false><<<dim3(4, MOBJ / 128), 256, 0, stream>>>(
        cur, agg, Wo1t, bo1, G, nullptr, MOBJ, 512, 640);
    // GEMM6: G @ Wo2 -> new entity (split bf16 state, + f32 last_entity on final step)
    float* cf = (t == T_ - 1) ? lastEnt : nullptr;
    gemm_k<0, false, true, true><<<dim3(4, MOBJ / 128), 256, 0, stream>>>(
        G, nullptr, Wo2t, bo2, nxt, cf, MOBJ, 512, 512);
    // location head on first 4 objects
    head_k<<<256, 64, 0, stream>>>(nxt, Wl, bl, outP, t);

    ushort_t* tmp = cur; cur = nxt; nxt = tmp;
  }
}

// Round 5
// 5998.594 us; speedup vs baseline: 2.0199x; 1.2022x over previous
//
#include <hip/hip_runtime.h>
#include <stdint.h>
#include <stddef.h>

// ---------- constants ----------
#define B_    64
#define N_    32
#define NREL_ 992
#define D_    512
#define E_    128
#define H_    512
#define T_    16
#define MROWS (B_ * NREL_)   // 63488
#define MOBJ  (B_ * N_)      // 2048

typedef unsigned short ushort_t;
typedef __attribute__((ext_vector_type(8))) short bf16x8;   // 8 bf16 = 4 VGPRs (MFMA A/B frag)
typedef __attribute__((ext_vector_type(4))) float f32x4;    // MFMA C/D frag

typedef __attribute__((address_space(1))) const void gvoid;
typedef __attribute__((address_space(3))) void lvoid;

__device__ __forceinline__ float bf2f(ushort_t u) {
  union { unsigned int i; float f; } v; v.i = ((unsigned int)u) << 16; return v.f;
}
__device__ __forceinline__ ushort_t f2bf(float f) {   // round-to-nearest-even
  union { float f; unsigned int i; } v; v.f = f;
  unsigned int u = v.i;
  u += 0x7FFFu + ((u >> 16) & 1u);
  return (ushort_t)(u >> 16);
}
__device__ __forceinline__ void gload_lds16(const void* g, void* l) {
  __builtin_amdgcn_global_load_lds((gvoid*)g, (lvoid*)l, 16, 0, 0);
}

// ---------- 128x128 MFMA GEMM, 3xBF16 fp32 emulation ----------
// Pipeline: double-buffered LDS K-tiles, counted vmcnt(8) (never 0 in steady
// state), raw s_barrier, 4 ds/MFMA-interleaved phases per K-tile, setprio(1)
// around MFMA clusters, XOR bank-swizzle (cbyte ^= (row&7)<<4) applied as
// pre-swizzled global SOURCE (linear gload_lds dest) + swizzled ds_read addr.
// MODE 0: A rows plain split [M][2K] = [hi K | lo K].
// MODE 2: logical row m = concat(ent[m](512), agg[m](128)); ent [m][1024] split,
//         agg (A2) [m][256] split. K=640.
// Outputs: WBF16 -> C split [row][2N]=[hi|lo]; WF32 -> Cf f32 [row][N].
template<int MODE, bool RELU, bool WBF16, bool WF32>
__global__ __launch_bounds__(256) void gemm_k(
    const ushort_t* __restrict__ A, const ushort_t* __restrict__ A2,
    const ushort_t* __restrict__ Bt, const float* __restrict__ bias,
    ushort_t* __restrict__ C, float* __restrict__ Cf,
    int M, int N, int K)
{
  __shared__ ushort_t As[2][128 * 64];   // [buf][row][64 elem] (128B rows)
  __shared__ ushort_t Bs[2][128 * 64];

  const int tid  = threadIdx.x;
  const int lane = tid & 63;
  const int wave = tid >> 6;

  // bijective XCD-chunked tile remap (m204)
  const int nwg  = gridDim.x * gridDim.y;
  const int orig = blockIdx.y * gridDim.x + blockIdx.x;
  const int xcd  = orig & 7;
  const int q    = nwg >> 3, r = nwg & 7;
  const int nid  = (xcd < r ? xcd * (q + 1) : r * (q + 1) + (xcd - r) * q) + (orig >> 3);
  const int m0 = (nid / gridDim.x) * 128;
  const int n0 = (nid % gridDim.x) * 128;

  const int wr = (wave >> 1) * 64;    // wave row offset in tile
  const int wc = (wave & 1) * 64;     // wave col offset in tile

  const int srow = tid >> 3;                          // 0..31 staging row in a round
  const int scol = (((tid & 7) ^ (srow & 7)) * 8);    // swizzled source col (elements)

  long aoff[4]; long aoff2[4];
#pragma unroll
  for (int rr = 0; rr < 4; ++rr) {
    int m = m0 + rr * 32 + srow;
    if (MODE == 0) { aoff[rr] = (long)m * (2 * K) + scol; aoff2[rr] = 0; }
    else           { aoff[rr] = (long)m * 1024 + scol; aoff2[rr] = (long)m * 256 + scol; }
  }
  long boff[4];
#pragma unroll
  for (int rr = 0; rr < 4; ++rr) boff[rr] = (long)(n0 + rr * 32 + srow) * (3 * K) + scol;

  const int NT = (3 * K) >> 6;   // K-tiles of 64

  // stage K-tile kt into LDS buffer b (8 gload_lds issues per thread)
  auto stage = [&](int kt, int b) {
    const int kpp = kt * 64;
    const int seg = (kpp >= 2 * K) ? 2 : ((kpp >= K) ? 1 : 0);
    const int k   = kpp - seg * K;
    const bool lop = (seg == 1);
#pragma unroll
    for (int rr = 0; rr < 4; ++rr) {
      const ushort_t* src;
      if (MODE == 0) {
        src = A + aoff[rr] + (lop ? K : 0) + k;
      } else {
        if (k < 512) src = A  + aoff[rr]  + (lop ? 512 : 0) + k;
        else         src = A2 + aoff2[rr] + (lop ? 128 : 0) + (k - 512);
      }
      gload_lds16(src, &As[b][(rr * 32 + wave * 8) * 64]);
    }
#pragma unroll
    for (int rr = 0; rr < 4; ++rr)
      gload_lds16(Bt + boff[rr] + kpp, &Bs[b][(rr * 32 + wave * 8) * 64]);
  };

  f32x4 zero = {0.f, 0.f, 0.f, 0.f};
  f32x4 acc[4][4];
#pragma unroll
  for (int i = 0; i < 4; ++i)
#pragma unroll
    for (int j = 0; j < 4; ++j) acc[i][j] = zero;

  // prologue: two K-tiles in flight
  stage(0, 0);
  if (NT > 1) stage(1, 1);

  for (int kt = 0; kt < NT; ++kt) {
    const int b = kt & 1;
    if (kt + 1 < NT) { asm volatile("s_waitcnt vmcnt(8)" ::: "memory"); }
    else             { asm volatile("s_waitcnt vmcnt(0)" ::: "memory"); }
    __builtin_amdgcn_s_barrier();
    asm volatile("" ::: "memory");

#pragma unroll
    for (int kk = 0; kk < 2; ++kk) {
      // swizzled read: 16B slot = (kk*4 + lane>>4) ^ (lane&7)
      const int cel = (((kk * 4 + (lane >> 4)) ^ (lane & 7)) << 3);
      bf16x8 af[4];
#pragma unroll
      for (int i = 0; i < 4; ++i)
        af[i] = *(const bf16x8*)&As[b][(wr + i * 16 + (lane & 15)) * 64 + cel];
#pragma unroll
      for (int jh = 0; jh < 2; ++jh) {
        bf16x8 bfr[2];
#pragma unroll
        for (int jj = 0; jj < 2; ++jj)
          bfr[jj] = *(const bf16x8*)&Bs[b][(wc + (jh * 2 + jj) * 16 + (lane & 15)) * 64 + cel];
        __builtin_amdgcn_s_setprio(1);
#pragma unroll
        for (int i = 0; i < 4; ++i)
#pragma unroll
          for (int jj = 0; jj < 2; ++jj)
            acc[i][jh * 2 + jj] =
                __builtin_amdgcn_mfma_f32_16x16x32_bf16(af[i], bfr[jj], acc[i][jh * 2 + jj], 0, 0, 0);
        __builtin_amdgcn_s_setprio(0);
      }
    }

    asm volatile("" ::: "memory");
    __builtin_amdgcn_s_barrier();
    asm volatile("" ::: "memory");
    if (kt + 2 < NT) stage(kt + 2, b);   // refill the buffer just consumed
  }

  // epilogue: C/D layout col=lane&15, row=(lane>>4)*4+reg
  const long strideC = 2 * (long)N;
#pragma unroll
  for (int j = 0; j < 4; ++j) {
    const int col = n0 + wc + j * 16 + (lane & 15);
    const float bv = bias ? bias[col] : 0.f;
#pragma unroll
    for (int i = 0; i < 4; ++i) {
      const int rowb = m0 + wr + i * 16 + (lane >> 4) * 4;
#pragma unroll
      for (int rr = 0; rr < 4; ++rr) {
        float v = acc[i][j][rr] + bv;
        if (RELU) v = fmaxf(v, 0.f);
        if (WBF16) {
          const ushort_t hi = f2bf(v);
          const float lof = v - bf2f(hi);
          C[(long)(rowb + rr) * strideC + col]     = hi;
          C[(long)(rowb + rr) * strideC + N + col] = f2bf(lof);
        }
        if (WF32) { if (Cf) Cf[(long)(rowb + rr) * N + col] = v; }
      }
    }
  }
}

// ---------- helpers ----------
__global__ void cvt_split_k(const float* __restrict__ x, ushort_t* __restrict__ y,
                            int total, int W) {
  int i = blockIdx.x * 256 + threadIdx.x;
  if (i >= total) return;
  int row = i / W, k = i - row * W;
  float v = x[i];
  ushort_t hi = f2bf(v);
  float lof = v - bf2f(hi);
  y[(long)row * (2 * W) + k]     = hi;
  y[(long)row * (2 * W) + W + k] = f2bf(lof);
}

// W[K][N] f32 -> Bt[n][3K] bf16 = [hi | hi | lo]
__global__ void transpose_cvt_split_k(const float* __restrict__ W, ushort_t* __restrict__ Bt,
                                      int K, int N) {
  int idx = blockIdx.x * 256 + threadIdx.x;
  if (idx >= K * N) return;
  int k = idx / N, n = idx - k * N;
  float v = W[idx];
  ushort_t hi = f2bf(v);
  float lof = v - bf2f(hi);
  ushort_t lo = f2bf(lof);
  long base = (long)n * (3 * K);
  Bt[base + k]         = hi;
  Bt[base + K + k]     = hi;
  Bt[base + 2 * K + k] = lo;
}

// Wr1 [1024][512] f32 -> WUVt [1024][1536]: col n<512 from Wr1[k][n] (U = src half),
// n>=512 from Wr1[512+k][n-512] (V = dst half). K=512 inner.
__global__ void tr_uv_k(const float* __restrict__ W, ushort_t* __restrict__ Bt) {
  int idx = blockIdx.x * 256 + threadIdx.x;
  if (idx >= 1024 * 512) return;
  int n = idx >> 9, k = idx & 511;
  float v = (n < 512) ? W[(long)k * 512 + n] : W[(long)(512 + k) * 512 + (n - 512)];
  ushort_t hi = f2bf(v);
  float lof = v - bf2f(hi);
  long base = (long)n * 1536;
  Bt[base + k]        = hi;
  Bt[base + 512 + k]  = hi;
  Bt[base + 1024 + k] = f2bf(lof);
}

__global__ void tables_k(int* __restrict__ srcN, int* __restrict__ dstN) {
  int m = blockIdx.x * 256 + threadIdx.x;
  if (m >= MROWS) return;
  int b = m / NREL_;
  int e = m - b * NREL_;
  int i = e / 31;
  int jj = e - i * 31;
  int j = jj + (jj >= i ? 1 : 0);
  srcN[m] = b * N_ + i;
  dstN[m] = b * N_ + j;
}

// H1c[rlocal] = relu(UV[src].U + UV[dst].V + br1), split hi/lo. 2 rows per block.
__global__ __launch_bounds__(256) void assemble_h1_k(
    const float* __restrict__ UV, const int* __restrict__ srcN,
    const int* __restrict__ dstN, const float* __restrict__ br1,
    ushort_t* __restrict__ H1c, long r0) {
  const int rlocal = blockIdx.x * 2 + (threadIdx.x >> 7);
  const long m = r0 + rlocal;
  const int k0 = (threadIdx.x & 127) * 4;
  const float4 u  = *(const float4*)&UV[(long)srcN[m] * 1024 + k0];
  const float4 w  = *(const float4*)&UV[(long)dstN[m] * 1024 + 512 + k0];
  const float4 bv = *(const float4*)&br1[k0];
  float v0 = fmaxf(u.x + w.x + bv.x, 0.f);
  float v1 = fmaxf(u.y + w.y + bv.y, 0.f);
  float v2 = fmaxf(u.z + w.z + bv.z, 0.f);
  float v3 = fmaxf(u.w + w.w + bv.w, 0.f);
  ushort4 hi, lo;
  hi.x = f2bf(v0); lo.x = f2bf(v0 - bf2f(hi.x));
  hi.y = f2bf(v1); lo.y = f2bf(v1 - bf2f(hi.y));
  hi.z = f2bf(v2); lo.z = f2bf(v2 - bf2f(hi.z));
  hi.w = f2bf(v3); lo.w = f2bf(v3 - bf2f(hi.w));
  *(ushort4*)&H1c[(long)rlocal * 1024 + k0]       = hi;
  *(ushort4*)&H1c[(long)rlocal * 1024 + 512 + k0] = lo;
}

// eff [MROWS][256] split -> agg [MOBJ][256] split (sum over 31 incoming edges)
__global__ void scatter_k(const ushort_t* __restrict__ eff, ushort_t* __restrict__ agg) {
  int bn = blockIdx.x;
  int b = bn >> 5, n = bn & 31, f = threadIdx.x;   // 128 threads = E_
  float s = 0.f;
#pragma unroll
  for (int i = 0; i < N_; ++i) {
    if (i == n) continue;
    int jj = (n < i) ? n : (n - 1);
    int e = i * 31 + jj;
    long base = ((long)b * NREL_ + e) * 256;
    s += bf2f(eff[base + f]) + bf2f(eff[base + 128 + f]);
  }
  long obase = ((long)b * N_ + n) * 256;
  ushort_t hi = f2bf(s);
  agg[obase + f]       = hi;
  agg[obase + 128 + f] = f2bf(s - bf2f(hi));
}

__global__ void head_k(const ushort_t* __restrict__ ent, const float* __restrict__ Wl,
                       const float* __restrict__ bl, float* __restrict__ out, int t) {
  int b = blockIdx.x >> 2, n = blockIdx.x & 3, lane = threadIdx.x;   // 64 threads
  const ushort_t* e = ent + (long)(b * N_ + n) * 1024;
  float a0 = 0.f, a1 = 0.f;
  for (int k = lane; k < D_; k += 64) {
    float v = bf2f(e[k]) + bf2f(e[512 + k]);
    a0 += v * Wl[2 * k]; a1 += v * Wl[2 * k + 1];
  }
#pragma unroll
  for (int s = 32; s > 0; s >>= 1) { a0 += __shfl_down(a0, s); a1 += __shfl_down(a1, s); }
  if (lane == 0) {
    out[((long)b * T_ + t) * 8 + n * 2 + 0] = a0 + bl[0];
    out[((long)b * T_ + t) * 8 + n * 2 + 1] = a1 + bl[1];
  }
}

// ---------- launch ----------
extern "C" void kernel_launch(void* const* d_in, const int* in_sizes, int n_in,
                              void* d_out, int out_size, void* d_ws, size_t ws_size,
                              hipStream_t stream) {
  const float* entity = (const float*)d_in[0];
  const float* Wr1 = (const float*)d_in[3];  const float* br1 = (const float*)d_in[4];
  const float* Wr2 = (const float*)d_in[5];  const float* br2 = (const float*)d_in[6];
  const float* Wr3 = (const float*)d_in[7];  const float* br3 = (const float*)d_in[8];
  const float* Wr4 = (const float*)d_in[9];  const float* br4 = (const float*)d_in[10];
  const float* Wo1 = (const float*)d_in[11]; const float* bo1 = (const float*)d_in[12];
  const float* Wo2 = (const float*)d_in[13]; const float* bo2 = (const float*)d_in[14];
  const float* Wl  = (const float*)d_in[15]; const float* bl  = (const float*)d_in[16];

  // fixed-size buffers ≈ 62.5 MB; chunk buffers = 2 * (MROWS/nchunk) * 1024 * 2 B
  const size_t fixedBytes = (size_t)70 * 1024 * 1024;
  int nchunk = 4;
  for (int c = 1; c <= 4; c *= 2) {
    size_t tot = fixedBytes + 2 * ((size_t)(MROWS / c) * 1024 * 2);
    if (tot <= ws_size) { nchunk = c; break; }
  }
  const int CH = MROWS / nchunk;

  char* ws = (char*)d_ws;
  size_t off = 0;
  auto alloc = [&](size_t bytes) -> void* {
    void* p = ws + off; off = (off + bytes + 255) & ~(size_t)255; return p;
  };
  ushort_t* entP0 = (ushort_t*)alloc((size_t)MOBJ * 1024 * 2);
  ushort_t* entP1 = (ushort_t*)alloc((size_t)MOBJ * 1024 * 2);
  float* UV = (float*)alloc((size_t)MOBJ * 1024 * 4);
  ushort_t* H3  = (ushort_t*)alloc((size_t)MROWS * 256 * 2);   // GEMM4 writes eff in place
  ushort_t* agg = (ushort_t*)alloc((size_t)MOBJ * 256 * 2);
  ushort_t* G   = (ushort_t*)alloc((size_t)MOBJ * 1024 * 2);
  ushort_t* WUVt = (ushort_t*)alloc((size_t)1024 * 1536 * 2);
  ushort_t* Wr2t = (ushort_t*)alloc((size_t)512 * 1536 * 2);
  ushort_t* Wr3t = (ushort_t*)alloc((size_t)128 * 1536 * 2);
  ushort_t* Wr4t = (ushort_t*)alloc((size_t)128 * 384 * 2);
  ushort_t* Wo1t = (ushort_t*)alloc((size_t)512 * 1920 * 2);
  ushort_t* Wo2t = (ushort_t*)alloc((size_t)512 * 1536 * 2);
  int* srcN = (int*)alloc((size_t)MROWS * 4);
  int* dstN = (int*)alloc((size_t)MROWS * 4);
  ushort_t* H1c = (ushort_t*)alloc((size_t)CH * 1024 * 2);
  ushort_t* H2c = (ushort_t*)alloc((size_t)CH * 1024 * 2);
  (void)in_sizes; (void)n_in; (void)out_size;

  tr_uv_k<<<(1024 * 512 + 255) / 256, 256, 0, stream>>>(Wr1, WUVt);
  transpose_cvt_split_k<<<(512 * 512 + 255) / 256, 256, 0, stream>>>(Wr2, Wr2t, 512, 512);
  transpose_cvt_split_k<<<(512 * 128 + 255) / 256, 256, 0, stream>>>(Wr3, Wr3t, 512, 128);
  transpose_cvt_split_k<<<(128 * 128 + 255) / 256, 256, 0, stream>>>(Wr4, Wr4t, 128, 128);
  transpose_cvt_split_k<<<(640 * 512 + 255) / 256, 256, 0, stream>>>(Wo1, Wo1t, 640, 512);
  transpose_cvt_split_k<<<(512 * 512 + 255) / 256, 256, 0, stream>>>(Wo2, Wo2t, 512, 512);
  tables_k<<<(MROWS + 255) / 256, 256, 0, stream>>>(srcN, dstN);
  cvt_split_k<<<(MOBJ * D_ + 255) / 256, 256, 0, stream>>>(entity, entP0, MOBJ * D_, D_);

  float* outP    = (float*)d_out;
  float* lastEnt = outP + (size_t)B_ * T_ * 8;

  ushort_t* cur = entP0;
  ushort_t* nxt = entP1;
  for (int t = 0; t < T_; ++t) {
    // UV = ent @ [Wr1_top | Wr1_bot]  (f32 out)  [2048 x 1024], K''=1536
    gemm_k<0, false, false, true><<<dim3(8, MOBJ / 128), 256, 0, stream>>>(
        cur, nullptr, WUVt, nullptr, nullptr, UV, MOBJ, 1024, 512);

    for (int c = 0; c < nchunk; ++c) {
      const long r0 = (long)c * CH;
      assemble_h1_k<<<CH / 2, 256, 0, stream>>>(UV, srcN, dstN, br1, H1c, r0);
      // GEMM2: H1c @ Wr2 -> H2c, relu
      gemm_k<0, true, true, false><<<dim3(4, CH / 128), 256, 0, stream>>>(
          H1c, nullptr, Wr2t, br2, H2c, nullptr, CH, 512, 512);
      // GEMM3: H2c @ Wr3 -> H3 chunk, relu
      gemm_k<0, true, true, false><<<dim3(1, CH / 128), 256, 0, stream>>>(
          H2c, nullptr, Wr3t, br3, H3 + r0 * 256, nullptr, CH, 128, 512);
    }
    // GEMM4: H3 @ Wr4 -> eff IN PLACE over H3
    gemm_k<0, true, true, false><<<dim3(1, MROWS / 128), 256, 0, stream>>>(
        H3, nullptr, Wr4t, br4, H3, nullptr, MROWS, 128, 128);
    scatter_k<<<MOBJ, 128, 0, stream>>>(H3, agg);
    // GEMM5: concat(ent, agg) [2048,640] @ Wo1 -> G, relu
    gemm_k<2, true, true, false><<<dim3(4, MOBJ / 128), 256, 0, stream>>>(
        cur, agg, Wo1t, bo1, G, nullptr, MOBJ, 512, 640);
    // GEMM6: G @ Wo2 -> new entity (+ f32 last_entity on final step)
    float* cf = (t == T_ - 1) ? lastEnt : nullptr;
    gemm_k<0, false, true, true><<<dim3(4, MOBJ / 128), 256, 0, stream>>>(
        G, nullptr, Wo2t, bo2, nxt, cf, MOBJ, 512, 512);
    head_k<<<256, 64, 0, stream>>>(nxt, Wl, bl, outP, t);

    ushort_t* tmp = cur; cur = nxt; nxt = tmp;
  }
}

// Round 6
// 5243.901 us; speedup vs baseline: 2.3105x; 1.1439x over previous
//
#include <hip/hip_runtime.h>
#include <stdint.h>
#include <stddef.h>

// ---------- constants ----------
#define B_    64
#define N_    32
#define NREL_ 992
#define D_    512
#define E_    128
#define H_    512
#define T_    16
#define MROWS (B_ * NREL_)   // 63488
#define MOBJ  (B_ * N_)      // 2048

typedef unsigned short ushort_t;
typedef __attribute__((ext_vector_type(8))) short bf16x8;   // 8 bf16 = 4 VGPRs (MFMA A/B frag)
typedef __attribute__((ext_vector_type(4))) float f32x4;    // MFMA C/D frag

typedef __attribute__((address_space(1))) const void gvoid;
typedef __attribute__((address_space(3))) void lvoid;

__device__ __forceinline__ float bf2f(ushort_t u) {
  union { unsigned int i; float f; } v; v.i = ((unsigned int)u) << 16; return v.f;
}
__device__ __forceinline__ ushort_t f2bf(float f) {   // round-to-nearest-even
  union { float f; unsigned int i; } v; v.f = f;
  unsigned int u = v.i;
  u += 0x7FFFu + ((u >> 16) & 1u);
  return (ushort_t)(u >> 16);
}
__device__ __forceinline__ void gload_lds16(const void* g, void* l) {
  __builtin_amdgcn_global_load_lds((gvoid*)g, (lvoid*)l, 16, 0, 0);
}

// ---------- TMx128 MFMA GEMM, 3xBF16 fp32 emulation ----------
// Double-buffered LDS K-tiles, counted vmcnt (never 0 in steady state), raw
// s_barrier, setprio(1) around MFMA clusters, XOR bank-swizzle applied as
// pre-swizzled global SOURCE (linear gload_lds dest) + swizzled ds_read addr.
// MODE 0: A rows plain split [M][2K] = [hi K | lo K].
// MODE 2: logical row m = concat(ent[m](512), agg[m](128)); K=640.
// TM in {64,128}: M-tile rows. 4 waves; wave owns (TM/2)x64.
template<int MODE, bool RELU, bool WBF16, bool WF32, int TM>
__global__ __launch_bounds__(256) void gemm_k(
    const ushort_t* __restrict__ A, const ushort_t* __restrict__ A2,
    const ushort_t* __restrict__ Bt, const float* __restrict__ bias,
    ushort_t* __restrict__ C, float* __restrict__ Cf,
    int M, int N, int K)
{
  constexpr int MI = TM / 32;          // A frag count per wave = stage rounds
  __shared__ ushort_t As[2][TM * 64];
  __shared__ ushort_t Bs[2][128 * 64];

  const int tid  = threadIdx.x;
  const int lane = tid & 63;
  const int wave = tid >> 6;

  // bijective XCD-chunked tile remap (m204)
  const int nwg  = gridDim.x * gridDim.y;
  const int orig = blockIdx.y * gridDim.x + blockIdx.x;
  const int xcd  = orig & 7;
  const int q    = nwg >> 3, r = nwg & 7;
  const int nid  = (xcd < r ? xcd * (q + 1) : r * (q + 1) + (xcd - r) * q) + (orig >> 3);
  const int m0 = (nid / gridDim.x) * TM;
  const int n0 = (nid % gridDim.x) * 128;

  const int wr = (wave >> 1) * (TM / 2);
  const int wc = (wave & 1) * 64;

  const int srow = tid >> 3;                          // 0..31 staging row in a round
  const int scol = (((tid & 7) ^ (srow & 7)) * 8);    // swizzled source col (elements)

  long aoff[MI]; long aoff2[MI];
#pragma unroll
  for (int rr = 0; rr < MI; ++rr) {
    int m = m0 + rr * 32 + srow;
    if (MODE == 0) { aoff[rr] = (long)m * (2 * K) + scol; aoff2[rr] = 0; }
    else           { aoff[rr] = (long)m * 1024 + scol; aoff2[rr] = (long)m * 256 + scol; }
  }
  long boff[4];
#pragma unroll
  for (int rr = 0; rr < 4; ++rr) boff[rr] = (long)(n0 + rr * 32 + srow) * (3 * K) + scol;

  const int NT = (3 * K) >> 6;

  auto stage = [&](int kt, int b) {
    const int kpp = kt * 64;
    const int seg = (kpp >= 2 * K) ? 2 : ((kpp >= K) ? 1 : 0);
    const int k   = kpp - seg * K;
    const bool lop = (seg == 1);
#pragma unroll
    for (int rr = 0; rr < MI; ++rr) {
      const ushort_t* src;
      if (MODE == 0) {
        src = A + aoff[rr] + (lop ? K : 0) + k;
      } else {
        if (k < 512) src = A  + aoff[rr]  + (lop ? 512 : 0) + k;
        else         src = A2 + aoff2[rr] + (lop ? 128 : 0) + (k - 512);
      }
      gload_lds16(src, &As[b][(rr * 32 + wave * 8) * 64]);
    }
#pragma unroll
    for (int rr = 0; rr < 4; ++rr)
      gload_lds16(Bt + boff[rr] + kpp, &Bs[b][(rr * 32 + wave * 8) * 64]);
  };

  f32x4 zero = {0.f, 0.f, 0.f, 0.f};
  f32x4 acc[MI][4];
#pragma unroll
  for (int i = 0; i < MI; ++i)
#pragma unroll
    for (int j = 0; j < 4; ++j) acc[i][j] = zero;

  stage(0, 0);
  if (NT > 1) stage(1, 1);

  for (int kt = 0; kt < NT; ++kt) {
    const int b = kt & 1;
    if (kt + 1 < NT) {
      if constexpr (TM == 128) asm volatile("s_waitcnt vmcnt(8)" ::: "memory");
      else                     asm volatile("s_waitcnt vmcnt(6)" ::: "memory");
    } else {
      asm volatile("s_waitcnt vmcnt(0)" ::: "memory");
    }
    __builtin_amdgcn_s_barrier();
    asm volatile("" ::: "memory");

#pragma unroll
    for (int kk = 0; kk < 2; ++kk) {
      const int cel = (((kk * 4 + (lane >> 4)) ^ (lane & 7)) << 3);
      bf16x8 af[MI];
#pragma unroll
      for (int i = 0; i < MI; ++i)
        af[i] = *(const bf16x8*)&As[b][(wr + i * 16 + (lane & 15)) * 64 + cel];
#pragma unroll
      for (int jh = 0; jh < 2; ++jh) {
        bf16x8 bfr[2];
#pragma unroll
        for (int jj = 0; jj < 2; ++jj)
          bfr[jj] = *(const bf16x8*)&Bs[b][(wc + (jh * 2 + jj) * 16 + (lane & 15)) * 64 + cel];
        __builtin_amdgcn_s_setprio(1);
#pragma unroll
        for (int i = 0; i < MI; ++i)
#pragma unroll
          for (int jj = 0; jj < 2; ++jj)
            acc[i][jh * 2 + jj] =
                __builtin_amdgcn_mfma_f32_16x16x32_bf16(af[i], bfr[jj], acc[i][jh * 2 + jj], 0, 0, 0);
        __builtin_amdgcn_s_setprio(0);
      }
    }

    asm volatile("" ::: "memory");
    __builtin_amdgcn_s_barrier();
    asm volatile("" ::: "memory");
    if (kt + 2 < NT) stage(kt + 2, b);
  }

  const long strideC = 2 * (long)N;
#pragma unroll
  for (int j = 0; j < 4; ++j) {
    const int col = n0 + wc + j * 16 + (lane & 15);
    const float bv = bias ? bias[col] : 0.f;
#pragma unroll
    for (int i = 0; i < MI; ++i) {
      const int rowb = m0 + wr + i * 16 + (lane >> 4) * 4;
#pragma unroll
      for (int rr = 0; rr < 4; ++rr) {
        float v = acc[i][j][rr] + bv;
        if (RELU) v = fmaxf(v, 0.f);
        if (WBF16) {
          const ushort_t hi = f2bf(v);
          const float lof = v - bf2f(hi);
          C[(long)(rowb + rr) * strideC + col]     = hi;
          C[(long)(rowb + rr) * strideC + N + col] = f2bf(lof);
        }
        if (WF32) { if (Cf) Cf[(long)(rowb + rr) * N + col] = v; }
      }
    }
  }
}

// ---------- fused GEMM3+GEMM4: eff = relu(relu(H2@W3+b3)@W4+b4) ----------
// N=128 for both. Phase 1 = standard pipelined GEMM (K=512, K''=1536) into acc;
// epilogue stores split H3 tile into the SAME 64KB LDS (4x [128][64] subtiles:
// hi0,hi1,lo0,lo1, XOR-swizzled). Phase 2 (K=128, K''=384, 6 K-tiles): A-frags
// from LDS, B-frags straight from global W4t (L2-hot, contiguous in K).
__global__ __launch_bounds__(256) void gemm34_k(
    const ushort_t* __restrict__ A, const ushort_t* __restrict__ W3t,
    const float* __restrict__ b3, const ushort_t* __restrict__ W4t,
    const float* __restrict__ b4, ushort_t* __restrict__ eff)
{
  __shared__ ushort_t SM[4][128 * 64];   // phase1: As0,As1,Bs0,Bs1; phase2: H3 hi0,hi1,lo0,lo1
  ushort_t* SMf = &SM[0][0];

  const int tid  = threadIdx.x;
  const int lane = tid & 63;
  const int wave = tid >> 6;

  const int nwg  = gridDim.y;
  const int orig = blockIdx.y;
  const int xcd  = orig & 7;
  const int q    = nwg >> 3, r = nwg & 7;
  const int nid  = (xcd < r ? xcd * (q + 1) : r * (q + 1) + (xcd - r) * q) + (orig >> 3);
  const int m0   = nid * 128;

  const int wr = (wave >> 1) * 64;
  const int wc = (wave & 1) * 64;
  const int srow = tid >> 3;
  const int scol = (((tid & 7) ^ (srow & 7)) * 8);

  long aoff[4];
#pragma unroll
  for (int rr = 0; rr < 4; ++rr) aoff[rr] = (long)(m0 + rr * 32 + srow) * 1024 + scol;
  long boff[4];
#pragma unroll
  for (int rr = 0; rr < 4; ++rr) boff[rr] = (long)(rr * 32 + srow) * 1536 + scol;

  auto stage = [&](int kt, int b) {
    const int kpp = kt * 64;
    const int seg = (kpp >= 1024) ? 2 : ((kpp >= 512) ? 1 : 0);
    const int k   = kpp - seg * 512;
    const bool lop = (seg == 1);
#pragma unroll
    for (int rr = 0; rr < 4; ++rr)
      gload_lds16(A + aoff[rr] + (lop ? 512 : 0) + k, &SM[b][(rr * 32 + wave * 8) * 64]);
#pragma unroll
    for (int rr = 0; rr < 4; ++rr)
      gload_lds16(W3t + boff[rr] + kpp, &SM[2 + b][(rr * 32 + wave * 8) * 64]);
  };

  f32x4 zero = {0.f, 0.f, 0.f, 0.f};
  f32x4 acc[4][4];
#pragma unroll
  for (int i = 0; i < 4; ++i)
#pragma unroll
    for (int j = 0; j < 4; ++j) acc[i][j] = zero;

  stage(0, 0);
  stage(1, 1);

  for (int kt = 0; kt < 24; ++kt) {
    const int b = kt & 1;
    if (kt + 1 < 24) asm volatile("s_waitcnt vmcnt(8)" ::: "memory");
    else             asm volatile("s_waitcnt vmcnt(0)" ::: "memory");
    __builtin_amdgcn_s_barrier();
    asm volatile("" ::: "memory");

#pragma unroll
    for (int kk = 0; kk < 2; ++kk) {
      const int cel = (((kk * 4 + (lane >> 4)) ^ (lane & 7)) << 3);
      bf16x8 af[4];
#pragma unroll
      for (int i = 0; i < 4; ++i)
        af[i] = *(const bf16x8*)&SM[b][(wr + i * 16 + (lane & 15)) * 64 + cel];
#pragma unroll
      for (int jh = 0; jh < 2; ++jh) {
        bf16x8 bfr[2];
#pragma unroll
        for (int jj = 0; jj < 2; ++jj)
          bfr[jj] = *(const bf16x8*)&SM[2 + b][(wc + (jh * 2 + jj) * 16 + (lane & 15)) * 64 + cel];
        __builtin_amdgcn_s_setprio(1);
#pragma unroll
        for (int i = 0; i < 4; ++i)
#pragma unroll
          for (int jj = 0; jj < 2; ++jj)
            acc[i][jh * 2 + jj] =
                __builtin_amdgcn_mfma_f32_16x16x32_bf16(af[i], bfr[jj], acc[i][jh * 2 + jj], 0, 0, 0);
        __builtin_amdgcn_s_setprio(0);
      }
    }

    asm volatile("" ::: "memory");
    __builtin_amdgcn_s_barrier();
    asm volatile("" ::: "memory");
    if (kt + 2 < 24) stage(kt + 2, b);
  }

  // epilogue 1: relu(acc + b3) -> split H3 tile in LDS (swizzled subtiles)
#pragma unroll
  for (int j = 0; j < 4; ++j) {
    const int col = wc + j * 16 + (lane & 15);       // 0..127
    const float bv = b3[col];
    const int thi = col >> 6, c = col & 63;
#pragma unroll
    for (int i = 0; i < 4; ++i) {
      const int rowb = wr + i * 16 + (lane >> 4) * 4;
#pragma unroll
      for (int rr = 0; rr < 4; ++rr) {
        const int row = rowb + rr;
        float v = fmaxf(acc[i][j][rr] + bv, 0.f);
        const ushort_t hi = f2bf(v);
        const ushort_t lo = f2bf(v - bf2f(hi));
        const int slot = ((c >> 3) ^ (row & 7)) * 8 + (c & 7);
        SMf[(thi * 128 + row) * 64 + slot]       = hi;
        SMf[((2 + thi) * 128 + row) * 64 + slot] = lo;
      }
    }
  }
  asm volatile("s_waitcnt lgkmcnt(0)" ::: "memory");
  __builtin_amdgcn_sched_barrier(0);
  __builtin_amdgcn_s_barrier();
  asm volatile("" ::: "memory");

  // phase 2: eff_tile = relu(H3_tile @ W4 + b4). A-tiles kt2: 0,1=hi 2,3=lo 4,5=hi.
  f32x4 acc2[4][4];
#pragma unroll
  for (int i = 0; i < 4; ++i)
#pragma unroll
    for (int j = 0; j < 4; ++j) acc2[i][j] = zero;

#pragma unroll
  for (int kt2 = 0; kt2 < 6; ++kt2) {
    const int phys = kt2 & 3;
#pragma unroll
    for (int kk = 0; kk < 2; ++kk) {
      const int cel = (((kk * 4 + (lane >> 4)) ^ (lane & 7)) << 3);
      bf16x8 af[4];
#pragma unroll
      for (int i = 0; i < 4; ++i)
        af[i] = *(const bf16x8*)&SMf[(phys * 128 + wr + i * 16 + (lane & 15)) * 64 + cel];
#pragma unroll
      for (int jh = 0; jh < 2; ++jh) {
        bf16x8 bfr[2];
#pragma unroll
        for (int jj = 0; jj < 2; ++jj) {
          const int col2 = wc + (jh * 2 + jj) * 16 + (lane & 15);
          bfr[jj] = *(const bf16x8*)&W4t[(long)col2 * 384 + kt2 * 64 + kk * 32 + (lane >> 4) * 8];
        }
        __builtin_amdgcn_s_setprio(1);
#pragma unroll
        for (int i = 0; i < 4; ++i)
#pragma unroll
          for (int jj = 0; jj < 2; ++jj)
            acc2[i][jh * 2 + jj] =
                __builtin_amdgcn_mfma_f32_16x16x32_bf16(af[i], bfr[jj], acc2[i][jh * 2 + jj], 0, 0, 0);
        __builtin_amdgcn_s_setprio(0);
      }
    }
  }

  // epilogue 2: relu(acc2 + b4) -> eff split [row][256]
#pragma unroll
  for (int j = 0; j < 4; ++j) {
    const int col = wc + j * 16 + (lane & 15);
    const float bv = b4[col];
#pragma unroll
    for (int i = 0; i < 4; ++i) {
      const int rowb = m0 + wr + i * 16 + (lane >> 4) * 4;
#pragma unroll
      for (int rr = 0; rr < 4; ++rr) {
        float v = fmaxf(acc2[i][j][rr] + bv, 0.f);
        const ushort_t hi = f2bf(v);
        eff[(long)(rowb + rr) * 256 + col]       = hi;
        eff[(long)(rowb + rr) * 256 + 128 + col] = f2bf(v - bf2f(hi));
      }
    }
  }
}

// ---------- helpers ----------
__global__ void cvt_split_k(const float* __restrict__ x, ushort_t* __restrict__ y,
                            int total, int W) {
  int i = blockIdx.x * 256 + threadIdx.x;
  if (i >= total) return;
  int row = i / W, k = i - row * W;
  float v = x[i];
  ushort_t hi = f2bf(v);
  float lof = v - bf2f(hi);
  y[(long)row * (2 * W) + k]     = hi;
  y[(long)row * (2 * W) + W + k] = f2bf(lof);
}

// W[K][N] f32 -> Bt[n][3K] bf16 = [hi | hi | lo]
__global__ void transpose_cvt_split_k(const float* __restrict__ W, ushort_t* __restrict__ Bt,
                                      int K, int N) {
  int idx = blockIdx.x * 256 + threadIdx.x;
  if (idx >= K * N) return;
  int k = idx / N, n = idx - k * N;
  float v = W[idx];
  ushort_t hi = f2bf(v);
  float lof = v - bf2f(hi);
  ushort_t lo = f2bf(lof);
  long base = (long)n * (3 * K);
  Bt[base + k]         = hi;
  Bt[base + K + k]     = hi;
  Bt[base + 2 * K + k] = lo;
}

// Wr1 [1024][512] f32 -> WUVt [1024][1536]
__global__ void tr_uv_k(const float* __restrict__ W, ushort_t* __restrict__ Bt) {
  int idx = blockIdx.x * 256 + threadIdx.x;
  if (idx >= 1024 * 512) return;
  int n = idx >> 9, k = idx & 511;
  float v = (n < 512) ? W[(long)k * 512 + n] : W[(long)(512 + k) * 512 + (n - 512)];
  ushort_t hi = f2bf(v);
  float lof = v - bf2f(hi);
  long base = (long)n * 1536;
  Bt[base + k]        = hi;
  Bt[base + 512 + k]  = hi;
  Bt[base + 1024 + k] = f2bf(lof);
}

__global__ void tables_k(int* __restrict__ srcN, int* __restrict__ dstN) {
  int m = blockIdx.x * 256 + threadIdx.x;
  if (m >= MROWS) return;
  int b = m / NREL_;
  int e = m - b * NREL_;
  int i = e / 31;
  int jj = e - i * 31;
  int j = jj + (jj >= i ? 1 : 0);
  srcN[m] = b * N_ + i;
  dstN[m] = b * N_ + j;
}

__global__ __launch_bounds__(256) void assemble_h1_k(
    const float* __restrict__ UV, const int* __restrict__ srcN,
    const int* __restrict__ dstN, const float* __restrict__ br1,
    ushort_t* __restrict__ H1c, long r0) {
  const int rlocal = blockIdx.x * 2 + (threadIdx.x >> 7);
  const long m = r0 + rlocal;
  const int k0 = (threadIdx.x & 127) * 4;
  const float4 u  = *(const float4*)&UV[(long)srcN[m] * 1024 + k0];
  const float4 w  = *(const float4*)&UV[(long)dstN[m] * 1024 + 512 + k0];
  const float4 bv = *(const float4*)&br1[k0];
  float v0 = fmaxf(u.x + w.x + bv.x, 0.f);
  float v1 = fmaxf(u.y + w.y + bv.y, 0.f);
  float v2 = fmaxf(u.z + w.z + bv.z, 0.f);
  float v3 = fmaxf(u.w + w.w + bv.w, 0.f);
  ushort4 hi, lo;
  hi.x = f2bf(v0); lo.x = f2bf(v0 - bf2f(hi.x));
  hi.y = f2bf(v1); lo.y = f2bf(v1 - bf2f(hi.y));
  hi.z = f2bf(v2); lo.z = f2bf(v2 - bf2f(hi.z));
  hi.w = f2bf(v3); lo.w = f2bf(v3 - bf2f(hi.w));
  *(ushort4*)&H1c[(long)rlocal * 1024 + k0]       = hi;
  *(ushort4*)&H1c[(long)rlocal * 1024 + 512 + k0] = lo;
}

__global__ void scatter_k(const ushort_t* __restrict__ eff, ushort_t* __restrict__ agg) {
  int bn = blockIdx.x;
  int b = bn >> 5, n = bn & 31, f = threadIdx.x;   // 128 threads = E_
  float s = 0.f;
#pragma unroll
  for (int i = 0; i < N_; ++i) {
    if (i == n) continue;
    int jj = (n < i) ? n : (n - 1);
    int e = i * 31 + jj;
    long base = ((long)b * NREL_ + e) * 256;
    s += bf2f(eff[base + f]) + bf2f(eff[base + 128 + f]);
  }
  long obase = ((long)b * N_ + n) * 256;
  ushort_t hi = f2bf(s);
  agg[obase + f]       = hi;
  agg[obase + 128 + f] = f2bf(s - bf2f(hi));
}

__global__ void head_k(const ushort_t* __restrict__ ent, const float* __restrict__ Wl,
                       const float* __restrict__ bl, float* __restrict__ out, int t) {
  int b = blockIdx.x >> 2, n = blockIdx.x & 3, lane = threadIdx.x;   // 64 threads
  const ushort_t* e = ent + (long)(b * N_ + n) * 1024;
  float a0 = 0.f, a1 = 0.f;
  for (int k = lane; k < D_; k += 64) {
    float v = bf2f(e[k]) + bf2f(e[512 + k]);
    a0 += v * Wl[2 * k]; a1 += v * Wl[2 * k + 1];
  }
#pragma unroll
  for (int s = 32; s > 0; s >>= 1) { a0 += __shfl_down(a0, s); a1 += __shfl_down(a1, s); }
  if (lane == 0) {
    out[((long)b * T_ + t) * 8 + n * 2 + 0] = a0 + bl[0];
    out[((long)b * T_ + t) * 8 + n * 2 + 1] = a1 + bl[1];
  }
}

// ---------- launch ----------
extern "C" void kernel_launch(void* const* d_in, const int* in_sizes, int n_in,
                              void* d_out, int out_size, void* d_ws, size_t ws_size,
                              hipStream_t stream) {
  const float* entity = (const float*)d_in[0];
  const float* Wr1 = (const float*)d_in[3];  const float* br1 = (const float*)d_in[4];
  const float* Wr2 = (const float*)d_in[5];  const float* br2 = (const float*)d_in[6];
  const float* Wr3 = (const float*)d_in[7];  const float* br3 = (const float*)d_in[8];
  const float* Wr4 = (const float*)d_in[9];  const float* br4 = (const float*)d_in[10];
  const float* Wo1 = (const float*)d_in[11]; const float* bo1 = (const float*)d_in[12];
  const float* Wo2 = (const float*)d_in[13]; const float* bo2 = (const float*)d_in[14];
  const float* Wl  = (const float*)d_in[15]; const float* bl  = (const float*)d_in[16];

  const size_t fixedBytes = (size_t)70 * 1024 * 1024;
  int nchunk = 4;
  for (int c = 1; c <= 4; c *= 2) {
    size_t tot = fixedBytes + 2 * ((size_t)(MROWS / c) * 1024 * 2);
    if (tot <= ws_size) { nchunk = c; break; }
  }
  const int CH = MROWS / nchunk;

  char* ws = (char*)d_ws;
  size_t off = 0;
  auto alloc = [&](size_t bytes) -> void* {
    void* p = ws + off; off = (off + bytes + 255) & ~(size_t)255; return p;
  };
  ushort_t* entP0 = (ushort_t*)alloc((size_t)MOBJ * 1024 * 2);
  ushort_t* entP1 = (ushort_t*)alloc((size_t)MOBJ * 1024 * 2);
  float* UV = (float*)alloc((size_t)MOBJ * 1024 * 4);
  ushort_t* eff = (ushort_t*)alloc((size_t)MROWS * 256 * 2);
  ushort_t* agg = (ushort_t*)alloc((size_t)MOBJ * 256 * 2);
  ushort_t* G   = (ushort_t*)alloc((size_t)MOBJ * 1024 * 2);
  ushort_t* WUVt = (ushort_t*)alloc((size_t)1024 * 1536 * 2);
  ushort_t* Wr2t = (ushort_t*)alloc((size_t)512 * 1536 * 2);
  ushort_t* Wr3t = (ushort_t*)alloc((size_t)128 * 1536 * 2);
  ushort_t* Wr4t = (ushort_t*)alloc((size_t)128 * 384 * 2);
  ushort_t* Wo1t = (ushort_t*)alloc((size_t)512 * 1920 * 2);
  ushort_t* Wo2t = (ushort_t*)alloc((size_t)512 * 1536 * 2);
  int* srcN = (int*)alloc((size_t)MROWS * 4);
  int* dstN = (int*)alloc((size_t)MROWS * 4);
  ushort_t* H1c = (ushort_t*)alloc((size_t)CH * 1024 * 2);
  ushort_t* H2c = (ushort_t*)alloc((size_t)CH * 1024 * 2);
  (void)in_sizes; (void)n_in; (void)out_size;

  tr_uv_k<<<(1024 * 512 + 255) / 256, 256, 0, stream>>>(Wr1, WUVt);
  transpose_cvt_split_k<<<(512 * 512 + 255) / 256, 256, 0, stream>>>(Wr2, Wr2t, 512, 512);
  transpose_cvt_split_k<<<(512 * 128 + 255) / 256, 256, 0, stream>>>(Wr3, Wr3t, 512, 128);
  transpose_cvt_split_k<<<(128 * 128 + 255) / 256, 256, 0, stream>>>(Wr4, Wr4t, 128, 128);
  transpose_cvt_split_k<<<(640 * 512 + 255) / 256, 256, 0, stream>>>(Wo1, Wo1t, 640, 512);
  transpose_cvt_split_k<<<(512 * 512 + 255) / 256, 256, 0, stream>>>(Wo2, Wo2t, 512, 512);
  tables_k<<<(MROWS + 255) / 256, 256, 0, stream>>>(srcN, dstN);
  cvt_split_k<<<(MOBJ * D_ + 255) / 256, 256, 0, stream>>>(entity, entP0, MOBJ * D_, D_);

  float* outP    = (float*)d_out;
  float* lastEnt = outP + (size_t)B_ * T_ * 8;

  ushort_t* cur = entP0;
  ushort_t* nxt = entP1;
  for (int t = 0; t < T_; ++t) {
    // UV = ent @ [Wr1_top | Wr1_bot]  (f32 out)  [2048 x 1024], TM=64 -> 256 blocks
    gemm_k<0, false, false, true, 64><<<dim3(8, MOBJ / 64), 256, 0, stream>>>(
        cur, nullptr, WUVt, nullptr, nullptr, UV, MOBJ, 1024, 512);

    for (int c = 0; c < nchunk; ++c) {
      const long r0 = (long)c * CH;
      assemble_h1_k<<<CH / 2, 256, 0, stream>>>(UV, srcN, dstN, br1, H1c, r0);
      // GEMM2: H1c @ Wr2 -> H2c, relu
      gemm_k<0, true, true, false, 128><<<dim3(4, CH / 128), 256, 0, stream>>>(
          H1c, nullptr, Wr2t, br2, H2c, nullptr, CH, 512, 512);
      // fused GEMM3+GEMM4: H2c -> eff chunk
      gemm34_k<<<dim3(1, CH / 128), 256, 0, stream>>>(
          H2c, Wr3t, br3, Wr4t, br4, eff + r0 * 256);
    }
    scatter_k<<<MOBJ, 128, 0, stream>>>(eff, agg);
    // GEMM5: concat(ent, agg) [2048,640] @ Wo1 -> G, relu  (TM=64 -> 128 blocks)
    gemm_k<2, true, true, false, 64><<<dim3(4, MOBJ / 64), 256, 0, stream>>>(
        cur, agg, Wo1t, bo1, G, nullptr, MOBJ, 512, 640);
    // GEMM6: G @ Wo2 -> new entity (+ f32 last_entity on final step)
    float* cf = (t == T_ - 1) ? lastEnt : nullptr;
    gemm_k<0, false, true, true, 64><<<dim3(4, MOBJ / 64), 256, 0, stream>>>(
        G, nullptr, Wo2t, bo2, nxt, cf, MOBJ, 512, 512);
    head_k<<<256, 64, 0, stream>>>(nxt, Wl, bl, outP, t);

    ushort_t* tmp = cur; cur = nxt; nxt = tmp;
  }
}